// Round 12
// baseline (1118.416 us; speedup 1.0000x reference)
//
#include <hip/hip_runtime.h>
#include <math.h>

// HydraScaleLM forward. Round 12: cvt kernels -> grid-stride (2048 blocks),
// fixing per-block overhead (k_cvtmega ran 73472 one-shot blocks at 2.7 TB/s).
// Everything else identical to round 11 (bgemmH head, XOR-swizzled bgemm,
// fused scanf, 33 dispatches).
// Shapes: B=2, S=512, D=1024, DEPTH=4, N=16, K=4, R=64, MLP=4096, V=32000. M=1024.

#define DEV __device__ __forceinline__
typedef unsigned int u32;
typedef unsigned short ushort;
typedef __bf16 bf16x8 __attribute__((ext_vector_type(8)));
typedef float f32x4 __attribute__((ext_vector_type(4)));
typedef ushort us8 __attribute__((ext_vector_type(8)));

DEV float silu_f(float x){ return x / (1.f + expf(-x)); }
DEV float gelu_f(float x){ return 0.5f * x * (1.f + erff(x * 0.70710678118654752f)); }
DEV float softplus_f(float x){ return (x > 20.f) ? x : log1pf(expf(x)); }
DEV ushort f2b(float f){
  u32 u = __builtin_bit_cast(u32, f);
  return (ushort)((u + 0x7fffu + ((u >> 16) & 1u)) >> 16);
}
DEV float b2f(ushort u){ return __builtin_bit_cast(float, (u32)u << 16); }

DEV void gl_lds16(const ushort* g, ushort* l){
  __builtin_amdgcn_global_load_lds(
      (const __attribute__((address_space(1))) u32*)g,
      (__attribute__((address_space(3))) u32*)l, 16, 0, 0);
}

// ---------------- weight conversion (grid-stride) ----------------
DEV void cvt_layer_unit(u32 j, const float* zWl, const float* pWl, const float* oWl,
                        const float* m1Wl, const float* m2Wl, ushort* wl)
{
  const float* src; u32 sj, dj;
  if (j < 294912u){
    dj = j;
    u32 row = j >> 8;
    if (row < 1024u){ src = zWl; sj = j; }
    else {
      u32 pr = row - 1024u;
      if (pr >= 96u){ ushort4 z4 = {0,0,0,0}; ((ushort4*)wl)[dj] = z4; return; }
      src = pWl; sj = pr*256u + (j & 255u);
    }
  } else if (j < 557056u){ u32 k = j - 294912u;  dj = j; src = oWl;  sj = k; }
  else if (j < 1605632u){ u32 k = j - 557056u;  dj = j; src = m1Wl; sj = k; }
  else                  { u32 k = j - 1605632u; dj = j; src = m2Wl; sj = k; }
  float4 v = ((const float4*)src)[sj];
  ushort4 o4; o4.x=f2b(v.x); o4.y=f2b(v.y); o4.z=f2b(v.z); o4.w=f2b(v.w);
  ((ushort4*)wl)[dj] = o4;
}

// all layers + head, grid-stride: units = 4*2,654,208 + 8,192,000 = 18,808,832
__global__ __launch_bounds__(256) void k_cvtmega(
    const float* __restrict__ zW, const float* __restrict__ pW,
    const float* __restrict__ oW, const float* __restrict__ m1W,
    const float* __restrict__ m2W, const float* __restrict__ hW,
    ushort* __restrict__ wall, ushort* __restrict__ whb)
{
  const u32 stride = gridDim.x * 256u;
  for (u32 i = blockIdx.x*256u + threadIdx.x; i < 18808832u; i += stride){
    if (i >= 10616832u){
      u32 j = i - 10616832u;
      float4 v = ((const float4*)hW)[j];
      ushort4 o4; o4.x=f2b(v.x); o4.y=f2b(v.y); o4.z=f2b(v.z); o4.w=f2b(v.w);
      ((ushort4*)whb)[j] = o4;
    } else {
      u32 l = i / 2654208u;
      u32 j = i - l*2654208u;
      cvt_layer_unit(j, zW + (size_t)l*1048576u, pW + (size_t)l*98304u,
                     oW + (size_t)l*1048576u, m1W + (size_t)l*4194304u,
                     m2W + (size_t)l*4194304u, wall + (size_t)l*10616832u);
    }
  }
}

__global__ __launch_bounds__(256) void k_cvtall(
    const float* __restrict__ zWl, const float* __restrict__ pWl,
    const float* __restrict__ oWl, const float* __restrict__ m1Wl,
    const float* __restrict__ m2Wl, ushort* __restrict__ wl)
{
  const u32 stride = gridDim.x * 256u;
  for (u32 j = blockIdx.x*256u + threadIdx.x; j < 2654208u; j += stride)
    cvt_layer_unit(j, zWl, pWl, oWl, m1Wl, m2Wl, wl);
}

__global__ __launch_bounds__(256) void k_cvt(const float* __restrict__ in, ushort* __restrict__ out, int n4){
  const u32 stride = gridDim.x * 256u;
  for (u32 i = blockIdx.x*256u + threadIdx.x; i < (u32)n4; i += stride){
    float4 v = ((const float4*)in)[i];
    ushort4 o; o.x=f2b(v.x); o.y=f2b(v.y); o.z=f2b(v.z); o.w=f2b(v.w);
    ((ushort4*)out)[i] = o;
  }
}

// ---------------- time embedding ----------------
__global__ __launch_bounds__(256) void k_temb1m(const int* __restrict__ ts, const float* __restrict__ w1,
                                                const float* __restrict__ b1, float* __restrict__ t1){
  __shared__ float sXT[1024];
  int bid = blockIdx.x;
  int tid = threadIdx.x;
  int b = (bid*4) >> 12;
  float tv = (float)ts[b];
  #pragma unroll
  for (int k=0;k<4;k++){
    int j = tid + k*256;
    int i = j & 511;
    float arg = tv * expf(-(9.210340371976184f/512.f) * (float)i);
    sXT[j] = (j < 512) ? sinf(arg) : cosf(arg);
  }
  __syncthreads();
  int o = bid*4 + (tid >> 6);
  int lane = tid & 63;
  int j = o & 4095;
  const float4* xr = (const float4*)sXT;
  const float4* wr = (const float4*)(w1 + (size_t)j*1024);
  float acc = 0.f;
  #pragma unroll
  for (int i=0;i<4;i++){
    float4 x4 = xr[i*64 + lane], w4 = wr[i*64 + lane];
    acc += x4.x*w4.x + x4.y*w4.y + x4.z*w4.z + x4.w*w4.w;
  }
  #pragma unroll
  for (int off=32; off; off>>=1) acc += __shfl_down(acc, off);
  if (lane==0) t1[o] = silu_f(acc + b1[j]);
}

__global__ __launch_bounds__(256) void k_temb2(const float* __restrict__ t1, const float* __restrict__ w2,
                                               const float* __restrict__ b2, float* __restrict__ t2){
  int o = blockIdx.x*4 + (threadIdx.x >> 6);
  int lane = threadIdx.x & 63;
  int b = o >> 10, j = o & 1023;
  const float4* xr = (const float4*)(t1 + b*4096);
  const float4* wr = (const float4*)(w2 + (size_t)j*4096);
  float acc = 0.f;
  #pragma unroll
  for (int i=0;i<16;i++){
    float4 x4 = xr[i*64 + lane], w4 = wr[i*64 + lane];
    acc += x4.x*w4.x + x4.y*w4.y + x4.z*w4.z + x4.w*w4.w;
  }
  #pragma unroll
  for (int off=32; off; off>>=1) acc += __shfl_down(acc, off);
  if (lane==0) t2[o] = acc + b2[j];
}

// ---------------- layernorm ----------------
DEV void ln_body(float4 v, const float* sc, const float* bi, int row, int t,
                 float* o, ushort* obf)
{
  float sum = v.x+v.y+v.z+v.w;
  float sq  = v.x*v.x+v.y*v.y+v.z*v.z+v.w*v.w;
  for (int o_=32;o_;o_>>=1){ sum += __shfl_down(sum,o_); sq += __shfl_down(sq,o_); }
  __shared__ float ps[8];
  int lane = t & 63, wid = t >> 6;
  if (lane==0){ ps[wid]=sum; ps[4+wid]=sq; }
  __syncthreads();
  float tot = ps[0]+ps[1]+ps[2]+ps[3];
  float tsq = ps[4]+ps[5]+ps[6]+ps[7];
  float m = tot * (1.f/1024.f);
  float var = tsq*(1.f/1024.f) - m*m;
  float r = rsqrtf(var + 1e-5f);
  float4 s4 = ((const float4*)sc)[t];
  float4 b4 = ((const float4*)bi)[t];
  float4 o4;
  o4.x = (v.x-m)*r*s4.x + b4.x;
  o4.y = (v.y-m)*r*s4.y + b4.y;
  o4.z = (v.z-m)*r*s4.z + b4.z;
  o4.w = (v.w-m)*r*s4.w + b4.w;
  ((float4*)(o + (size_t)row*1024))[t] = o4;
  ushort4 ob; ob.x=f2b(o4.x); ob.y=f2b(o4.y); ob.z=f2b(o4.z); ob.w=f2b(o4.w);
  ((ushort4*)(obf + (size_t)row*1024))[t] = ob;
}

__global__ __launch_bounds__(256) void k_ln(const float* __restrict__ x, const float* __restrict__ sc,
                                            const float* __restrict__ bi, float* __restrict__ o,
                                            ushort* __restrict__ obf){
  int row = blockIdx.x, t = threadIdx.x;
  float4 v = ((const float4*)(x + (size_t)row*1024))[t];
  ln_body(v, sc, bi, row, t, o, obf);
}

__global__ __launch_bounds__(256) void k_embln(const int* __restrict__ ids, const float* __restrict__ tok,
                                               const float* __restrict__ t2, const float* __restrict__ sc,
                                               const float* __restrict__ bi, float* __restrict__ xout,
                                               float* __restrict__ o, ushort* __restrict__ obf){
  int row = blockIdx.x, t = threadIdx.x;
  int id = ids[row];
  float4 v = ((const float4*)(tok + (size_t)id*1024))[t];
  float4 e = ((const float4*)(t2 + ((row >> 9) << 10)))[t];
  v.x += e.x; v.y += e.y; v.z += e.z; v.w += e.w;
  ((float4*)(xout + (size_t)row*1024))[t] = v;
  ln_body(v, sc, bi, row, t, o, obf);
}

// ---------------- fused dt + conv + chunk-parallel SSM scan + ypost ----------------
__global__ __launch_bounds__(512) void k_scanf(
    const ushort* __restrict__ pb64, const float* __restrict__ dtW, const float* __restrict__ dtb,
    const float* __restrict__ xn, const float* __restrict__ p, const float* __restrict__ alog,
    const float* __restrict__ z, const float* __restrict__ Dp,
    const float* __restrict__ cw, ushort* __restrict__ y2b)
{
  const int bid = blockIdx.x;
  const int logical = (bid & 7)*256 + (bid >> 3);
  const int d = logical & 1023;
  const int b = logical >> 10;
  const int tid = threadIdx.x;
  const int c = tid >> 4, n = tid & 15;
  const float al = alog[d*16 + n];
  const float A = -expf(al);
  const float invA = 1.f/(A + 1e-10f);
  const bool tiny = fabsf(A) < 1e-8f;
  const float dscale = Dp[d];
  const float cw0 = cw[d*4], cw1 = cw[d*4+1], cw2 = cw[d*4+2], cw3 = cw[d*4+3];
  const size_t base = (size_t)b*512*1024 + d;
  const float* pp = p + (size_t)b*512*96;
  const int s0 = c*16;

  __shared__ float sXN[520];
  __shared__ float sDT[512], sZ[512];
  __shared__ float sA[512], sB[512], sH[512];
  __shared__ float sDTW[64];

  if (tid < 64) sDTW[tid] = dtW[d*64 + tid];
  {
    int s = tid - 3;
    sXN[tid] = (s >= 0) ? xn[base + (size_t)s*1024] : 0.f;
    if (tid < 3) sXN[512 + tid] = xn[base + (size_t)(509 + tid)*1024];
    sZ[tid] = z[base + (size_t)tid*1024];
  }
  __syncthreads();

  {
    const us8* pr = (const us8*)(pb64 + (size_t)(b*512 + tid)*64);
    float acc = 0.f;
    #pragma unroll
    for (int q=0;q<8;q++){
      us8 v = pr[q];
      #pragma unroll
      for (int e=0;e<8;e++)
        acc = fmaf(b2f(v[e]), sDTW[q*8+e], acc);
    }
    sDT[tid] = softplus_f(acc + dtb[d]);
  }
  __syncthreads();

  float At[16], inp[16];
  float h = 0.f, pa = 1.f;
  #pragma unroll
  for (int s8=0; s8<16; s8++){
    int s = s0 + s8;
    float uv = silu_f(sXN[s]*cw0 + sXN[s+1]*cw1 + sXN[s+2]*cw2 + sXN[s+3]*cw3);
    float dtv = sDT[s];
    float Bpv = pp[s*96 + 64 + n];
    float a  = expf(dtv*A);
    float bt = tiny ? dtv : (a-1.f)*invA;
    At[s8] = a;
    float ip = bt*Bpv*uv;
    inp[s8] = ip;
    h = a*h + ip;
    pa *= a;
  }
  sA[tid]=pa; sB[tid]=h;
  __syncthreads();
  if (tid < 16){
    float H = 0.f;
    #pragma unroll
    for (int c2=0;c2<32;c2++){
      sH[c2*16+tid] = H;
      H = sA[c2*16+tid]*H + sB[c2*16+tid];
    }
  }
  __syncthreads();

  h = sH[tid];
  #pragma unroll
  for (int s8=0; s8<16; s8++){
    int s = s0 + s8;
    h = At[s8]*h + inp[s8];
    float Cpv = pp[s*96 + 80 + n];
    float cc = Cpv*h;
    cc += __shfl_xor(cc,1);
    cc += __shfl_xor(cc,2);
    cc += __shfl_xor(cc,4);
    cc += __shfl_xor(cc,8);
    if (n==0){
      float uv = silu_f(sXN[s]*cw0 + sXN[s+1]*cw1 + sXN[s+2]*cw2 + sXN[s+3]*cw3);
      float zv = sZ[s];
      y2b[base + (size_t)s*1024] = f2b((cc + uv*dscale) * (zv/(1.f+expf(-zv))));
    }
  }
}

// ---------------- bf16 MFMA GEMM (128 x TN), gl_lds + XOR swizzle ----------------
template<int TN, int EPI, bool OBF>
__global__ __launch_bounds__(256) void k_bgemm(
    const ushort* __restrict__ A,
    const ushort* __restrict__ W,
    const float* __restrict__ bias,
    const float* __restrict__ resid,
    void* __restrict__ Cout,
    int ldc, int nmax, int K,
    float* __restrict__ pout, ushort* __restrict__ pbout)
{
  constexpr int WN = (TN==128)?2:1;
  constexpr int WM = 4/WN;
  constexpr int MR = 128/(WM*16);
  constexpr int NR = TN/(WN*16);

  __shared__ ushort As[128*64] __attribute__((aligned(16)));
  __shared__ ushort Bs[TN*64]  __attribute__((aligned(16)));
  const int t = threadIdx.x;
  const int w = t >> 6, lane = t & 63;
  const int wn = w % WN, wm = w / WN;
  const int m0 = blockIdx.y * 128;
  const int n0 = blockIdx.x * TN;

  f32x4 acc[MR][NR];
  #pragma unroll
  for (int i=0;i<MR;i++)
    #pragma unroll
    for (int j=0;j<NR;j++) acc[i][j] = (f32x4){0.f,0.f,0.f,0.f};

  const int srow = (lane >> 3);
  const int scol = (((lane & 7) ^ srow)) * 8;

  for (int k0 = 0; k0 < K; k0 += 64){
    __syncthreads();
    #pragma unroll
    for (int i=0;i<4;i++){
      int chunk = i*4 + w;
      int row = chunk*8 + srow;
      gl_lds16(A + (size_t)(m0 + row)*K + k0 + scol, &As[chunk*512]);
    }
    #pragma unroll
    for (int i=0;i<TN/32;i++){
      int chunk = i*4 + w;
      int row = chunk*8 + srow;
      gl_lds16(W + (size_t)(n0 + row)*K + k0 + scol, &Bs[chunk*512]);
    }
    __syncthreads();
    const int fr = lane & 15;
    const int hi = lane >> 4;
    #pragma unroll
    for (int kk=0; kk<2; ++kk){
      bf16x8 a[MR], b[NR];
      const int cofs = (((kk<<2) | hi) ^ (fr & 7)) * 8;
      #pragma unroll
      for (int am=0; am<MR; am++)
        a[am] = *(const bf16x8*)&As[(wm*(MR*16) + am*16 + fr)*64 + cofs];
      #pragma unroll
      for (int bn=0; bn<NR; bn++)
        b[bn] = *(const bf16x8*)&Bs[(wn*(NR*16) + bn*16 + fr)*64 + cofs];
      #pragma unroll
      for (int am=0; am<MR; am++)
        #pragma unroll
        for (int bn=0; bn<NR; bn++)
          acc[am][bn] = __builtin_amdgcn_mfma_f32_16x16x32_bf16(a[am], b[bn], acc[am][bn], 0, 0, 0);
    }
  }

  #pragma unroll
  for (int am=0; am<MR; am++){
    #pragma unroll
    for (int bn=0; bn<NR; bn++){
      int r0 = m0 + wm*(MR*16) + am*16 + ((lane>>4)<<2);
      int cc = n0 + wn*(NR*16) + bn*16 + (lane&15);
      if (cc >= nmax) continue;
      float bv = 0.f;
      if constexpr (EPI==1 || EPI==2 || EPI==5) bv = bias[cc];
      #pragma unroll
      for (int r=0; r<4; r++){
        float v = acc[am][bn][r];
        if constexpr (EPI==1 || EPI==2 || EPI==5) v += bv;
        if constexpr (EPI==2) v = gelu_f(v);
        if constexpr (EPI==4 || EPI==5) v += resid[(size_t)(r0+r)*ldc + cc];
        if constexpr (EPI==6){
          if (cc < 1024) ((float*)Cout)[(size_t)(r0+r)*ldc + cc] = v;
          else {
            int pc = cc - 1024;
            if (pc < 96) pout[(size_t)(r0+r)*96 + pc] = v;
            if (pc < 64) pbout[(size_t)(r0+r)*64 + pc] = f2b(v);
          }
        } else if constexpr (OBF){
          ((ushort*)Cout)[(size_t)(r0+r)*ldc + cc] = f2b(v);
        } else {
          ((float*)Cout)[(size_t)(r0+r)*ldc + cc] = v;
        }
      }
    }
  }
}

// ---------------- head GEMM: 256x128 tile, 512 thr / 8 waves, XCD-grouped ----------------
__global__ __launch_bounds__(512) void k_bgemmH(
    const ushort* __restrict__ A,
    const ushort* __restrict__ W,
    const float* __restrict__ bias,
    float* __restrict__ Cout,
    int ldc, int K)
{
  __shared__ ushort As[256*64] __attribute__((aligned(16)));
  __shared__ ushort Bs[128*64] __attribute__((aligned(16)));
  const int t = threadIdx.x;
  const int w = t >> 6, lane = t & 63;
  const int wn = w & 1, wm = w >> 1;
  const int bid = blockIdx.x;
  const int logical = (bid & 7)*125 + (bid >> 3);
  const int m0 = (logical & 3) * 256;
  const int n0 = (logical >> 2) * 128;

  f32x4 acc[4][4];
  #pragma unroll
  for (int i=0;i<4;i++)
    #pragma unroll
    for (int j=0;j<4;j++) acc[i][j] = (f32x4){0.f,0.f,0.f,0.f};

  const int srow = (lane >> 3);
  const int scol = (((lane & 7) ^ srow)) * 8;

  for (int k0 = 0; k0 < K; k0 += 64){
    __syncthreads();
    #pragma unroll
    for (int i=0;i<4;i++){
      int chunk = i*8 + w;
      int row = chunk*8 + srow;
      gl_lds16(A + (size_t)(m0 + row)*K + k0 + scol, &As[chunk*512]);
    }
    #pragma unroll
    for (int i=0;i<2;i++){
      int chunk = i*8 + w;
      int row = chunk*8 + srow;
      gl_lds16(W + (size_t)(n0 + row)*K + k0 + scol, &Bs[chunk*512]);
    }
    __syncthreads();
    const int fr = lane & 15;
    const int hi = lane >> 4;
    #pragma unroll
    for (int kk=0; kk<2; ++kk){
      bf16x8 a[4], b[4];
      const int cofs = (((kk<<2) | hi) ^ (fr & 7)) * 8;
      #pragma unroll
      for (int am=0; am<4; am++)
        a[am] = *(const bf16x8*)&As[(wm*64 + am*16 + fr)*64 + cofs];
      #pragma unroll
      for (int bn=0; bn<4; bn++)
        b[bn] = *(const bf16x8*)&Bs[(wn*64 + bn*16 + fr)*64 + cofs];
      #pragma unroll
      for (int am=0; am<4; am++)
        #pragma unroll
        for (int bn=0; bn<4; bn++)
          acc[am][bn] = __builtin_amdgcn_mfma_f32_16x16x32_bf16(a[am], b[bn], acc[am][bn], 0, 0, 0);
    }
  }

  #pragma unroll
  for (int am=0; am<4; am++){
    #pragma unroll
    for (int bn=0; bn<4; bn++){
      int r0 = m0 + wm*64 + am*16 + ((lane>>4)<<2);
      int cc = n0 + wn*64 + bn*16 + (lane&15);
      float bv = bias[cc];
      #pragma unroll
      for (int r=0; r<4; r++)
        Cout[(size_t)(r0+r)*ldc + cc] = acc[am][bn][r] + bv;
    }
  }
}

extern "C" void kernel_launch(void* const* d_in, const int* in_sizes, int n_in,
                              void* d_out, int out_size, void* d_ws, size_t ws_size,
                              hipStream_t stream)
{
  const int*   ids    = (const int*)d_in[0];
  const int*   tsteps = (const int*)d_in[1];
  const float* tok    = (const float*)d_in[2];
  const float* tw1    = (const float*)d_in[3];
  const float* tb1    = (const float*)d_in[4];
  const float* tw2    = (const float*)d_in[5];
  const float* tb2    = (const float*)d_in[6];
  const float* n1s    = (const float*)d_in[7];
  const float* n1b    = (const float*)d_in[8];
  // d_in[9] = xW, unused by the reference
  const float* zW     = (const float*)d_in[10];
  const float* pW     = (const float*)d_in[11];
  const float* cW     = (const float*)d_in[12];
  const float* dtW    = (const float*)d_in[13];
  const float* dtb    = (const float*)d_in[14];
  const float* alog   = (const float*)d_in[15];
  const float* Dp     = (const float*)d_in[16];
  const float* oW     = (const float*)d_in[17];
  const float* n2s    = (const float*)d_in[18];
  const float* n2b    = (const float*)d_in[19];
  const float* m1W    = (const float*)d_in[20];
  const float* m1b    = (const float*)d_in[21];
  const float* m2W    = (const float*)d_in[22];
  const float* m2b    = (const float*)d_in[23];
  const float* nos    = (const float*)d_in[24];
  const float* nob    = (const float*)d_in[25];
  const float* hW     = (const float*)d_in[26];
  const float* hb     = (const float*)d_in[27];

  float* ws = (float*)d_ws;
  float*  x    = ws;
  float*  xn   = ws + 1048576;
  float*  z    = ws + 2097152;
  float*  p    = ws + 3145728;
  ushort* pb64 = (ushort*)(ws + 3244032);
  float*  t1   = ws + 3276800;
  float*  t2   = ws + 3284992;
  ushort* xnb  = (ushort*)(ws + 3670016);
  ushort* y2b  = (ushort*)(ws + 4194304);
  ushort* h1b  = (ushort*)(ws + 5242880);

  const size_t WBASE = 7340032;
  const size_t WL_US = 10616832;
  const bool big = ws_size >= 179830784ull;
  ushort* wall = (ushort*)(ws + WBASE);
  ushort* whb  = big ? (ushort*)(ws + WBASE + 4*(WL_US/2))
                     : (ushort*)(ws + WBASE);

  dim3 blk(256);
  if (big)
    k_cvtmega<<<dim3(2048), blk, 0, stream>>>(zW, pW, oW, m1W, m2W, hW, wall, whb);
  k_temb1m<<<dim3(2048), blk, 0, stream>>>(tsteps, tw1, tb1, t1);
  k_temb2<<<dim3(512),  blk, 0, stream>>>(t1, tw2, tb2, t2);

  for (int l=0; l<4; l++){
    ushort* wl = wall + (big ? (size_t)l*WL_US : 0);
    ushort* wzp = wl;
    ushort* wo  = wl + 1179648;
    ushort* wm1 = wl + 2228224;
    ushort* wm2 = wl + 6422528;
    if (!big)
      k_cvtall<<<dim3(2048), blk, 0, stream>>>(
          zW + (size_t)l*1048576, pW + (size_t)l*98304, oW + (size_t)l*1048576,
          m1W + (size_t)l*4194304, m2W + (size_t)l*4194304, wl);
    if (l == 0)
      k_embln<<<dim3(1024), blk, 0, stream>>>(ids, tok, t2, n1s, n1b, x, xn, xnb);
    else
      k_ln<<<dim3(1024), blk, 0, stream>>>(x, n1s + l*1024, n1b + l*1024, xn, xnb);
    k_bgemm<64,6,false><<<dim3(18,8), blk, 0, stream>>>(xnb, wzp, nullptr, nullptr, z,
                                                        1024, 1152, 1024, p, pb64);
    k_scanf<<<dim3(2048), dim3(512), 0, stream>>>(pb64, dtW + (size_t)l*65536, dtb + l*1024,
                                                  xn, p, alog + l*16384, z, Dp + l*1024,
                                                  cW + l*4096, y2b);
    k_bgemm<64,4,false><<<dim3(16,8), blk, 0, stream>>>(y2b, wo, nullptr, x, x,
                                                        1024, 1024, 1024, nullptr, nullptr);
    k_ln<<<dim3(1024), blk, 0, stream>>>(x, n2s + l*1024, n2b + l*1024, xn, xnb);
    k_bgemm<128,2,true><<<dim3(32,8), blk, 0, stream>>>(xnb, wm1, m1b + l*4096, nullptr, h1b,
                                                        4096, 4096, 1024, nullptr, nullptr);
    k_bgemm<64,5,false><<<dim3(16,8), blk, 0, stream>>>(h1b, wm2, m2b + l*1024, x, x,
                                                        1024, 1024, 4096, nullptr, nullptr);
  }
  k_ln<<<dim3(1024), blk, 0, stream>>>(x, nos, nob, xn, xnb);

  if (big){
    k_bgemmH<<<dim3(1000), dim3(512), 0, stream>>>(xnb, whb, hb, (float*)d_out, 32000, 1024);
  } else {
    for (int h=0; h<2; h++){
      k_cvt<<<dim3(2048), blk, 0, stream>>>(hW + (size_t)h*16384000, whb, 4096000);
      k_bgemm<128,1,false><<<dim3(125,8), blk, 0, stream>>>(xnb, whb, hb + h*16000, nullptr,
                                                            (float*)d_out + h*16000,
                                                            32000, 16000, 1024, nullptr, nullptr);
    }
  }
}

// Round 13
// 1042.171 us; speedup vs baseline: 1.0732x; 1.0732x over previous
//
#include <hip/hip_runtime.h>
#include <math.h>

// HydraScaleLM forward. Round 13:
//  - cvtmega reverted to one-shot 73k-block form (grid-stride was -15% BW)
//  - layer GEMMs: TM=64xTN=64 tile variant -> 256-288 block grids (full CU
//    coverage, was 128-144 = half the chip idle). m1 (128x128, 256 blks) and
//    head (bgemmH 256x128, 1000 blks) unchanged.
// Shapes: B=2, S=512, D=1024, DEPTH=4, N=16, K=4, R=64, MLP=4096, V=32000. M=1024.

#define DEV __device__ __forceinline__
typedef unsigned int u32;
typedef unsigned short ushort;
typedef __bf16 bf16x8 __attribute__((ext_vector_type(8)));
typedef float f32x4 __attribute__((ext_vector_type(4)));
typedef ushort us8 __attribute__((ext_vector_type(8)));

DEV float silu_f(float x){ return x / (1.f + expf(-x)); }
DEV float gelu_f(float x){ return 0.5f * x * (1.f + erff(x * 0.70710678118654752f)); }
DEV float softplus_f(float x){ return (x > 20.f) ? x : log1pf(expf(x)); }
DEV ushort f2b(float f){
  u32 u = __builtin_bit_cast(u32, f);
  return (ushort)((u + 0x7fffu + ((u >> 16) & 1u)) >> 16);
}
DEV float b2f(ushort u){ return __builtin_bit_cast(float, (u32)u << 16); }

DEV void gl_lds16(const ushort* g, ushort* l){
  __builtin_amdgcn_global_load_lds(
      (const __attribute__((address_space(1))) u32*)g,
      (__attribute__((address_space(3))) u32*)l, 16, 0, 0);
}

// ---------------- weight conversion (one-shot blocks; round-11 proven form) ----------------
DEV void cvt_layer_unit(u32 j, const float* zWl, const float* pWl, const float* oWl,
                        const float* m1Wl, const float* m2Wl, ushort* wl)
{
  const float* src; u32 sj, dj;
  if (j < 294912u){
    dj = j;
    u32 row = j >> 8;
    if (row < 1024u){ src = zWl; sj = j; }
    else {
      u32 pr = row - 1024u;
      if (pr >= 96u){ ushort4 z4 = {0,0,0,0}; ((ushort4*)wl)[dj] = z4; return; }
      src = pWl; sj = pr*256u + (j & 255u);
    }
  } else if (j < 557056u){ u32 k = j - 294912u;  dj = j; src = oWl;  sj = k; }
  else if (j < 1605632u){ u32 k = j - 557056u;  dj = j; src = m1Wl; sj = k; }
  else                  { u32 k = j - 1605632u; dj = j; src = m2Wl; sj = k; }
  float4 v = ((const float4*)src)[sj];
  ushort4 o4; o4.x=f2b(v.x); o4.y=f2b(v.y); o4.z=f2b(v.z); o4.w=f2b(v.w);
  ((ushort4*)wl)[dj] = o4;
}

__global__ __launch_bounds__(256) void k_cvtmega(
    const float* __restrict__ zW, const float* __restrict__ pW,
    const float* __restrict__ oW, const float* __restrict__ m1W,
    const float* __restrict__ m2W, const float* __restrict__ hW,
    ushort* __restrict__ wall, ushort* __restrict__ whb)
{
  u32 i = blockIdx.x*256u + threadIdx.x;
  if (i >= 18808832u) return;
  if (i >= 10616832u){
    u32 j = i - 10616832u;
    float4 v = ((const float4*)hW)[j];
    ushort4 o4; o4.x=f2b(v.x); o4.y=f2b(v.y); o4.z=f2b(v.z); o4.w=f2b(v.w);
    ((ushort4*)whb)[j] = o4;
    return;
  }
  u32 l = i / 2654208u;
  u32 j = i - l*2654208u;
  cvt_layer_unit(j, zW + (size_t)l*1048576u, pW + (size_t)l*98304u,
                 oW + (size_t)l*1048576u, m1W + (size_t)l*4194304u,
                 m2W + (size_t)l*4194304u, wall + (size_t)l*10616832u);
}

__global__ __launch_bounds__(256) void k_cvtall(
    const float* __restrict__ zWl, const float* __restrict__ pWl,
    const float* __restrict__ oWl, const float* __restrict__ m1Wl,
    const float* __restrict__ m2Wl, ushort* __restrict__ wl)
{
  u32 j = blockIdx.x*256u + threadIdx.x;
  if (j >= 2654208u) return;
  cvt_layer_unit(j, zWl, pWl, oWl, m1Wl, m2Wl, wl);
}

__global__ __launch_bounds__(256) void k_cvt(const float* __restrict__ in, ushort* __restrict__ out, int n4){
  int i = blockIdx.x*256 + threadIdx.x;
  if (i >= n4) return;
  float4 v = ((const float4*)in)[i];
  ushort4 o; o.x=f2b(v.x); o.y=f2b(v.y); o.z=f2b(v.z); o.w=f2b(v.w);
  ((ushort4*)out)[i] = o;
}

// ---------------- time embedding ----------------
__global__ __launch_bounds__(256) void k_temb1m(const int* __restrict__ ts, const float* __restrict__ w1,
                                                const float* __restrict__ b1, float* __restrict__ t1){
  __shared__ float sXT[1024];
  int bid = blockIdx.x;
  int tid = threadIdx.x;
  int b = (bid*4) >> 12;
  float tv = (float)ts[b];
  #pragma unroll
  for (int k=0;k<4;k++){
    int j = tid + k*256;
    int i = j & 511;
    float arg = tv * expf(-(9.210340371976184f/512.f) * (float)i);
    sXT[j] = (j < 512) ? sinf(arg) : cosf(arg);
  }
  __syncthreads();
  int o = bid*4 + (tid >> 6);
  int lane = tid & 63;
  int j = o & 4095;
  const float4* xr = (const float4*)sXT;
  const float4* wr = (const float4*)(w1 + (size_t)j*1024);
  float acc = 0.f;
  #pragma unroll
  for (int i=0;i<4;i++){
    float4 x4 = xr[i*64 + lane], w4 = wr[i*64 + lane];
    acc += x4.x*w4.x + x4.y*w4.y + x4.z*w4.z + x4.w*w4.w;
  }
  #pragma unroll
  for (int off=32; off; off>>=1) acc += __shfl_down(acc, off);
  if (lane==0) t1[o] = silu_f(acc + b1[j]);
}

__global__ __launch_bounds__(256) void k_temb2(const float* __restrict__ t1, const float* __restrict__ w2,
                                               const float* __restrict__ b2, float* __restrict__ t2){
  int o = blockIdx.x*4 + (threadIdx.x >> 6);
  int lane = threadIdx.x & 63;
  int b = o >> 10, j = o & 1023;
  const float4* xr = (const float4*)(t1 + b*4096);
  const float4* wr = (const float4*)(w2 + (size_t)j*4096);
  float acc = 0.f;
  #pragma unroll
  for (int i=0;i<16;i++){
    float4 x4 = xr[i*64 + lane], w4 = wr[i*64 + lane];
    acc += x4.x*w4.x + x4.y*w4.y + x4.z*w4.z + x4.w*w4.w;
  }
  #pragma unroll
  for (int off=32; off; off>>=1) acc += __shfl_down(acc, off);
  if (lane==0) t2[o] = acc + b2[j];
}

// ---------------- layernorm ----------------
DEV void ln_body(float4 v, const float* sc, const float* bi, int row, int t,
                 float* o, ushort* obf)
{
  float sum = v.x+v.y+v.z+v.w;
  float sq  = v.x*v.x+v.y*v.y+v.z*v.z+v.w*v.w;
  for (int o_=32;o_;o_>>=1){ sum += __shfl_down(sum,o_); sq += __shfl_down(sq,o_); }
  __shared__ float ps[8];
  int lane = t & 63, wid = t >> 6;
  if (lane==0){ ps[wid]=sum; ps[4+wid]=sq; }
  __syncthreads();
  float tot = ps[0]+ps[1]+ps[2]+ps[3];
  float tsq = ps[4]+ps[5]+ps[6]+ps[7];
  float m = tot * (1.f/1024.f);
  float var = tsq*(1.f/1024.f) - m*m;
  float r = rsqrtf(var + 1e-5f);
  float4 s4 = ((const float4*)sc)[t];
  float4 b4 = ((const float4*)bi)[t];
  float4 o4;
  o4.x = (v.x-m)*r*s4.x + b4.x;
  o4.y = (v.y-m)*r*s4.y + b4.y;
  o4.z = (v.z-m)*r*s4.z + b4.z;
  o4.w = (v.w-m)*r*s4.w + b4.w;
  ((float4*)(o + (size_t)row*1024))[t] = o4;
  ushort4 ob; ob.x=f2b(o4.x); ob.y=f2b(o4.y); ob.z=f2b(o4.z); ob.w=f2b(o4.w);
  ((ushort4*)(obf + (size_t)row*1024))[t] = ob;
}

__global__ __launch_bounds__(256) void k_ln(const float* __restrict__ x, const float* __restrict__ sc,
                                            const float* __restrict__ bi, float* __restrict__ o,
                                            ushort* __restrict__ obf){
  int row = blockIdx.x, t = threadIdx.x;
  float4 v = ((const float4*)(x + (size_t)row*1024))[t];
  ln_body(v, sc, bi, row, t, o, obf);
}

__global__ __launch_bounds__(256) void k_embln(const int* __restrict__ ids, const float* __restrict__ tok,
                                               const float* __restrict__ t2, const float* __restrict__ sc,
                                               const float* __restrict__ bi, float* __restrict__ xout,
                                               float* __restrict__ o, ushort* __restrict__ obf){
  int row = blockIdx.x, t = threadIdx.x;
  int id = ids[row];
  float4 v = ((const float4*)(tok + (size_t)id*1024))[t];
  float4 e = ((const float4*)(t2 + ((row >> 9) << 10)))[t];
  v.x += e.x; v.y += e.y; v.z += e.z; v.w += e.w;
  ((float4*)(xout + (size_t)row*1024))[t] = v;
  ln_body(v, sc, bi, row, t, o, obf);
}

// ---------------- fused dt + conv + chunk-parallel SSM scan + ypost ----------------
__global__ __launch_bounds__(512) void k_scanf(
    const ushort* __restrict__ pb64, const float* __restrict__ dtW, const float* __restrict__ dtb,
    const float* __restrict__ xn, const float* __restrict__ p, const float* __restrict__ alog,
    const float* __restrict__ z, const float* __restrict__ Dp,
    const float* __restrict__ cw, ushort* __restrict__ y2b)
{
  const int bid = blockIdx.x;
  const int logical = (bid & 7)*256 + (bid >> 3);
  const int d = logical & 1023;
  const int b = logical >> 10;
  const int tid = threadIdx.x;
  const int c = tid >> 4, n = tid & 15;
  const float al = alog[d*16 + n];
  const float A = -expf(al);
  const float invA = 1.f/(A + 1e-10f);
  const bool tiny = fabsf(A) < 1e-8f;
  const float dscale = Dp[d];
  const float cw0 = cw[d*4], cw1 = cw[d*4+1], cw2 = cw[d*4+2], cw3 = cw[d*4+3];
  const size_t base = (size_t)b*512*1024 + d;
  const float* pp = p + (size_t)b*512*96;
  const int s0 = c*16;

  __shared__ float sXN[520];
  __shared__ float sDT[512], sZ[512];
  __shared__ float sA[512], sB[512], sH[512];
  __shared__ float sDTW[64];

  if (tid < 64) sDTW[tid] = dtW[d*64 + tid];
  {
    int s = tid - 3;
    sXN[tid] = (s >= 0) ? xn[base + (size_t)s*1024] : 0.f;
    if (tid < 3) sXN[512 + tid] = xn[base + (size_t)(509 + tid)*1024];
    sZ[tid] = z[base + (size_t)tid*1024];
  }
  __syncthreads();

  {
    const us8* pr = (const us8*)(pb64 + (size_t)(b*512 + tid)*64);
    float acc = 0.f;
    #pragma unroll
    for (int q=0;q<8;q++){
      us8 v = pr[q];
      #pragma unroll
      for (int e=0;e<8;e++)
        acc = fmaf(b2f(v[e]), sDTW[q*8+e], acc);
    }
    sDT[tid] = softplus_f(acc + dtb[d]);
  }
  __syncthreads();

  float At[16], inp[16];
  float h = 0.f, pa = 1.f;
  #pragma unroll
  for (int s8=0; s8<16; s8++){
    int s = s0 + s8;
    float uv = silu_f(sXN[s]*cw0 + sXN[s+1]*cw1 + sXN[s+2]*cw2 + sXN[s+3]*cw3);
    float dtv = sDT[s];
    float Bpv = pp[s*96 + 64 + n];
    float a  = expf(dtv*A);
    float bt = tiny ? dtv : (a-1.f)*invA;
    At[s8] = a;
    float ip = bt*Bpv*uv;
    inp[s8] = ip;
    h = a*h + ip;
    pa *= a;
  }
  sA[tid]=pa; sB[tid]=h;
  __syncthreads();
  if (tid < 16){
    float H = 0.f;
    #pragma unroll
    for (int c2=0;c2<32;c2++){
      sH[c2*16+tid] = H;
      H = sA[c2*16+tid]*H + sB[c2*16+tid];
    }
  }
  __syncthreads();

  h = sH[tid];
  #pragma unroll
  for (int s8=0; s8<16; s8++){
    int s = s0 + s8;
    h = At[s8]*h + inp[s8];
    float Cpv = pp[s*96 + 80 + n];
    float cc = Cpv*h;
    cc += __shfl_xor(cc,1);
    cc += __shfl_xor(cc,2);
    cc += __shfl_xor(cc,4);
    cc += __shfl_xor(cc,8);
    if (n==0){
      float uv = silu_f(sXN[s]*cw0 + sXN[s+1]*cw1 + sXN[s+2]*cw2 + sXN[s+3]*cw3);
      float zv = sZ[s];
      y2b[base + (size_t)s*1024] = f2b((cc + uv*dscale) * (zv/(1.f+expf(-zv))));
    }
  }
}

// ---------------- bf16 MFMA GEMM (TM x TN), gl_lds + XOR swizzle ----------------
// Combos used: (64,64): 4 waves 2x2, 2x2 frags, LDS 16KB, grids 256-288 blocks;
//              (128,128): 4 waves 2x2, 4x4 frags, LDS 32KB.
// EPI: 0 none, 1 bias, 2 bias+gelu, 4 resid, 5 bias+resid, 6 z/p split.
template<int TM, int TN, int EPI, bool OBF>
__global__ __launch_bounds__(256) void k_bgemm(
    const ushort* __restrict__ A,
    const ushort* __restrict__ W,
    const float* __restrict__ bias,
    const float* __restrict__ resid,
    void* __restrict__ Cout,
    int ldc, int nmax, int K,
    float* __restrict__ pout, ushort* __restrict__ pbout)
{
  constexpr int WN = 2;
  constexpr int WM = 2;
  constexpr int MR = TM/(WM*16);   // 2 (TM=64) or 4 (TM=128)
  constexpr int NR = TN/(WN*16);   // 2 or 4

  __shared__ ushort As[TM*64] __attribute__((aligned(16)));
  __shared__ ushort Bs[TN*64] __attribute__((aligned(16)));
  const int t = threadIdx.x;
  const int w = t >> 6, lane = t & 63;
  const int wn = w % WN, wm = w / WN;
  const int m0 = blockIdx.y * TM;
  const int n0 = blockIdx.x * TN;

  f32x4 acc[MR][NR];
  #pragma unroll
  for (int i=0;i<MR;i++)
    #pragma unroll
    for (int j=0;j<NR;j++) acc[i][j] = (f32x4){0.f,0.f,0.f,0.f};

  const int srow = (lane >> 3);
  const int scol = (((lane & 7) ^ srow)) * 8;

  for (int k0 = 0; k0 < K; k0 += 64){
    __syncthreads();
    #pragma unroll
    for (int i=0;i<TM/32;i++){
      int chunk = i*4 + w;
      int row = chunk*8 + srow;
      gl_lds16(A + (size_t)(m0 + row)*K + k0 + scol, &As[chunk*512]);
    }
    #pragma unroll
    for (int i=0;i<TN/32;i++){
      int chunk = i*4 + w;
      int row = chunk*8 + srow;
      gl_lds16(W + (size_t)(n0 + row)*K + k0 + scol, &Bs[chunk*512]);
    }
    __syncthreads();
    const int fr = lane & 15;
    const int hi = lane >> 4;
    #pragma unroll
    for (int kk=0; kk<2; ++kk){
      bf16x8 a[MR], b[NR];
      const int cofs = (((kk<<2) | hi) ^ (fr & 7)) * 8;
      #pragma unroll
      for (int am=0; am<MR; am++)
        a[am] = *(const bf16x8*)&As[(wm*(MR*16) + am*16 + fr)*64 + cofs];
      #pragma unroll
      for (int bn=0; bn<NR; bn++)
        b[bn] = *(const bf16x8*)&Bs[(wn*(NR*16) + bn*16 + fr)*64 + cofs];
      #pragma unroll
      for (int am=0; am<MR; am++)
        #pragma unroll
        for (int bn=0; bn<NR; bn++)
          acc[am][bn] = __builtin_amdgcn_mfma_f32_16x16x32_bf16(a[am], b[bn], acc[am][bn], 0, 0, 0);
    }
  }

  #pragma unroll
  for (int am=0; am<MR; am++){
    #pragma unroll
    for (int bn=0; bn<NR; bn++){
      int r0 = m0 + wm*(MR*16) + am*16 + ((lane>>4)<<2);
      int cc = n0 + wn*(NR*16) + bn*16 + (lane&15);
      if (cc >= nmax) continue;
      float bv = 0.f;
      if constexpr (EPI==1 || EPI==2 || EPI==5) bv = bias[cc];
      #pragma unroll
      for (int r=0; r<4; r++){
        float v = acc[am][bn][r];
        if constexpr (EPI==1 || EPI==2 || EPI==5) v += bv;
        if constexpr (EPI==2) v = gelu_f(v);
        if constexpr (EPI==4 || EPI==5) v += resid[(size_t)(r0+r)*ldc + cc];
        if constexpr (EPI==6){
          if (cc < 1024) ((float*)Cout)[(size_t)(r0+r)*ldc + cc] = v;
          else {
            int pc = cc - 1024;
            if (pc < 96) pout[(size_t)(r0+r)*96 + pc] = v;
            if (pc < 64) pbout[(size_t)(r0+r)*64 + pc] = f2b(v);
          }
        } else if constexpr (OBF){
          ((ushort*)Cout)[(size_t)(r0+r)*ldc + cc] = f2b(v);
        } else {
          ((float*)Cout)[(size_t)(r0+r)*ldc + cc] = v;
        }
      }
    }
  }
}

// ---------------- head GEMM: 256x128 tile, 512 thr / 8 waves, XCD-grouped ----------------
__global__ __launch_bounds__(512) void k_bgemmH(
    const ushort* __restrict__ A,
    const ushort* __restrict__ W,
    const float* __restrict__ bias,
    float* __restrict__ Cout,
    int ldc, int K)
{
  __shared__ ushort As[256*64] __attribute__((aligned(16)));
  __shared__ ushort Bs[128*64] __attribute__((aligned(16)));
  const int t = threadIdx.x;
  const int w = t >> 6, lane = t & 63;
  const int wn = w & 1, wm = w >> 1;
  const int bid = blockIdx.x;
  const int logical = (bid & 7)*125 + (bid >> 3);
  const int m0 = (logical & 3) * 256;
  const int n0 = (logical >> 2) * 128;

  f32x4 acc[4][4];
  #pragma unroll
  for (int i=0;i<4;i++)
    #pragma unroll
    for (int j=0;j<4;j++) acc[i][j] = (f32x4){0.f,0.f,0.f,0.f};

  const int srow = (lane >> 3);
  const int scol = (((lane & 7) ^ srow)) * 8;

  for (int k0 = 0; k0 < K; k0 += 64){
    __syncthreads();
    #pragma unroll
    for (int i=0;i<4;i++){
      int chunk = i*8 + w;
      int row = chunk*8 + srow;
      gl_lds16(A + (size_t)(m0 + row)*K + k0 + scol, &As[chunk*512]);
    }
    #pragma unroll
    for (int i=0;i<2;i++){
      int chunk = i*8 + w;
      int row = chunk*8 + srow;
      gl_lds16(W + (size_t)(n0 + row)*K + k0 + scol, &Bs[chunk*512]);
    }
    __syncthreads();
    const int fr = lane & 15;
    const int hi = lane >> 4;
    #pragma unroll
    for (int kk=0; kk<2; ++kk){
      bf16x8 a[4], b[4];
      const int cofs = (((kk<<2) | hi) ^ (fr & 7)) * 8;
      #pragma unroll
      for (int am=0; am<4; am++)
        a[am] = *(const bf16x8*)&As[(wm*64 + am*16 + fr)*64 + cofs];
      #pragma unroll
      for (int bn=0; bn<4; bn++)
        b[bn] = *(const bf16x8*)&Bs[(wn*64 + bn*16 + fr)*64 + cofs];
      #pragma unroll
      for (int am=0; am<4; am++)
        #pragma unroll
        for (int bn=0; bn<4; bn++)
          acc[am][bn] = __builtin_amdgcn_mfma_f32_16x16x32_bf16(a[am], b[bn], acc[am][bn], 0, 0, 0);
    }
  }

  #pragma unroll
  for (int am=0; am<4; am++){
    #pragma unroll
    for (int bn=0; bn<4; bn++){
      int r0 = m0 + wm*64 + am*16 + ((lane>>4)<<2);
      int cc = n0 + wn*64 + bn*16 + (lane&15);
      float bv = bias[cc];
      #pragma unroll
      for (int r=0; r<4; r++)
        Cout[(size_t)(r0+r)*ldc + cc] = acc[am][bn][r] + bv;
    }
  }
}

extern "C" void kernel_launch(void* const* d_in, const int* in_sizes, int n_in,
                              void* d_out, int out_size, void* d_ws, size_t ws_size,
                              hipStream_t stream)
{
  const int*   ids    = (const int*)d_in[0];
  const int*   tsteps = (const int*)d_in[1];
  const float* tok    = (const float*)d_in[2];
  const float* tw1    = (const float*)d_in[3];
  const float* tb1    = (const float*)d_in[4];
  const float* tw2    = (const float*)d_in[5];
  const float* tb2    = (const float*)d_in[6];
  const float* n1s    = (const float*)d_in[7];
  const float* n1b    = (const float*)d_in[8];
  // d_in[9] = xW, unused by the reference
  const float* zW     = (const float*)d_in[10];
  const float* pW     = (const float*)d_in[11];
  const float* cW     = (const float*)d_in[12];
  const float* dtW    = (const float*)d_in[13];
  const float* dtb    = (const float*)d_in[14];
  const float* alog   = (const float*)d_in[15];
  const float* Dp     = (const float*)d_in[16];
  const float* oW     = (const float*)d_in[17];
  const float* n2s    = (const float*)d_in[18];
  const float* n2b    = (const float*)d_in[19];
  const float* m1W    = (const float*)d_in[20];
  const float* m1b    = (const float*)d_in[21];
  const float* m2W    = (const float*)d_in[22];
  const float* m2b    = (const float*)d_in[23];
  const float* nos    = (const float*)d_in[24];
  const float* nob    = (const float*)d_in[25];
  const float* hW     = (const float*)d_in[26];
  const float* hb     = (const float*)d_in[27];

  float* ws = (float*)d_ws;
  float*  x    = ws;
  float*  xn   = ws + 1048576;
  float*  z    = ws + 2097152;
  float*  p    = ws + 3145728;
  ushort* pb64 = (ushort*)(ws + 3244032);
  float*  t1   = ws + 3276800;
  float*  t2   = ws + 3284992;
  ushort* xnb  = (ushort*)(ws + 3670016);
  ushort* y2b  = (ushort*)(ws + 4194304);
  ushort* h1b  = (ushort*)(ws + 5242880);

  const size_t WBASE = 7340032;
  const size_t WL_US = 10616832;
  const bool big = ws_size >= 179830784ull;
  ushort* wall = (ushort*)(ws + WBASE);
  ushort* whb  = big ? (ushort*)(ws + WBASE + 4*(WL_US/2))
                     : (ushort*)(ws + WBASE);

  dim3 blk(256);
  if (big)
    k_cvtmega<<<dim3(73472), blk, 0, stream>>>(zW, pW, oW, m1W, m2W, hW, wall, whb);
  k_temb1m<<<dim3(2048), blk, 0, stream>>>(tsteps, tw1, tb1, t1);
  k_temb2<<<dim3(512),  blk, 0, stream>>>(t1, tw2, tb2, t2);

  for (int l=0; l<4; l++){
    ushort* wl = wall + (big ? (size_t)l*WL_US : 0);
    ushort* wzp = wl;
    ushort* wo  = wl + 1179648;
    ushort* wm1 = wl + 2228224;
    ushort* wm2 = wl + 6422528;
    if (!big)
      k_cvtall<<<dim3(10368), blk, 0, stream>>>(
          zW + (size_t)l*1048576, pW + (size_t)l*98304, oW + (size_t)l*1048576,
          m1W + (size_t)l*4194304, m2W + (size_t)l*4194304, wl);
    if (l == 0)
      k_embln<<<dim3(1024), blk, 0, stream>>>(ids, tok, t2, n1s, n1b, x, xn, xnb);
    else
      k_ln<<<dim3(1024), blk, 0, stream>>>(x, n1s + l*1024, n1b + l*1024, xn, xnb);
    // z | p | pb64 in one GEMM (N=1152 packed), 64x64 tiles: 288 blocks
    k_bgemm<64,64,6,false><<<dim3(18,16), blk, 0, stream>>>(xnb, wzp, nullptr, nullptr, z,
                                                            1024, 1152, 1024, p, pb64);
    k_scanf<<<dim3(2048), dim3(512), 0, stream>>>(pb64, dtW + (size_t)l*65536, dtb + l*1024,
                                                  xn, p, alog + l*16384, z, Dp + l*1024,
                                                  cW + l*4096, y2b);
    // x += y2 @ oW^T   (64x64 tiles: 256 blocks)
    k_bgemm<64,64,4,false><<<dim3(16,16), blk, 0, stream>>>(y2b, wo, nullptr, x, x,
                                                            1024, 1024, 1024, nullptr, nullptr);
    k_ln<<<dim3(1024), blk, 0, stream>>>(x, n2s + l*1024, n2b + l*1024, xn, xnb);
    k_bgemm<128,128,2,true><<<dim3(32,8), blk, 0, stream>>>(xnb, wm1, m1b + l*4096, nullptr, h1b,
                                                            4096, 4096, 1024, nullptr, nullptr);
    // m2 (K=4096), 64x64 tiles: 256 blocks
    k_bgemm<64,64,5,false><<<dim3(16,16), blk, 0, stream>>>(h1b, wm2, m2b + l*1024, x, x,
                                                            1024, 1024, 4096, nullptr, nullptr);
  }
  k_ln<<<dim3(1024), blk, 0, stream>>>(x, nos, nob, xn, xnb);

  if (big){
    k_bgemmH<<<dim3(1000), dim3(512), 0, stream>>>(xnb, whb, hb, (float*)d_out, 32000, 1024);
  } else {
    for (int h=0; h<2; h++){
      k_cvt<<<dim3(16000), blk, 0, stream>>>(hW + (size_t)h*16384000, whb, 4096000);
      k_bgemm<128,128,1,false><<<dim3(125,8), blk, 0, stream>>>(xnb, whb, hb + h*16000, nullptr,
                                                                (float*)d_out + h*16000,
                                                                32000, 16000, 1024, nullptr, nullptr);
    }
  }
}

// Round 14
// 981.992 us; speedup vs baseline: 1.1389x; 1.0613x over previous
//
#include <hip/hip_runtime.h>
#include <math.h>

// HydraScaleLM forward. Round 14:
//  - cvtmega/cvtall: pair-width conversion (2x float4 load -> 1x us8 16B store,
//    half the store instructions; one-shot blocks kept per round-12 lesson)
//  - m1 GEMM -> 64x64 tiles (1024 blocks, 4/CU; coverage lever from round 13)
// All else = round 13 (bgemmH head, XOR-swizzled bgemm, fused scanf).
// Shapes: B=2, S=512, D=1024, DEPTH=4, N=16, K=4, R=64, MLP=4096, V=32000. M=1024.

#define DEV __device__ __forceinline__
typedef unsigned int u32;
typedef unsigned short ushort;
typedef __bf16 bf16x8 __attribute__((ext_vector_type(8)));
typedef float f32x4 __attribute__((ext_vector_type(4)));
typedef ushort us8 __attribute__((ext_vector_type(8)));

DEV float silu_f(float x){ return x / (1.f + expf(-x)); }
DEV float gelu_f(float x){ return 0.5f * x * (1.f + erff(x * 0.70710678118654752f)); }
DEV float softplus_f(float x){ return (x > 20.f) ? x : log1pf(expf(x)); }
DEV ushort f2b(float f){
  u32 u = __builtin_bit_cast(u32, f);
  return (ushort)((u + 0x7fffu + ((u >> 16) & 1u)) >> 16);
}
DEV float b2f(ushort u){ return __builtin_bit_cast(float, (u32)u << 16); }

DEV void gl_lds16(const ushort* g, ushort* l){
  __builtin_amdgcn_global_load_lds(
      (const __attribute__((address_space(1))) u32*)g,
      (__attribute__((address_space(3))) u32*)l, 16, 0, 0);
}

DEV us8 cvt2(float4 a, float4 b){
  us8 v;
  v[0]=f2b(a.x); v[1]=f2b(a.y); v[2]=f2b(a.z); v[3]=f2b(a.w);
  v[4]=f2b(b.x); v[5]=f2b(b.y); v[6]=f2b(b.z); v[7]=f2b(b.w);
  return v;
}

// ---------------- weight conversion (pair-width, one-shot blocks) ----------------
// per-layer packed block (ushort4 units): zp 294912 | o 262144 | m1 1048576 | m2 1048576
// all segment boundaries even -> a pair (unit j, j+1), j even, never straddles.
DEV void cvt_layer_pair(u32 j /*even*/, const float* zWl, const float* pWl, const float* oWl,
                        const float* m1Wl, const float* m2Wl, ushort* wl)
{
  const float* src; u32 sj;
  if (j < 294912u){
    u32 row = j >> 8;
    if (row < 1024u){ src = zWl; sj = j; }
    else {
      u32 pr = row - 1024u;
      if (pr >= 96u){ us8 z8 = {0,0,0,0,0,0,0,0}; *(us8*)&wl[j*4u] = z8; return; }
      src = pWl; sj = pr*256u + (j & 255u);   // j&255 <= 254, pair stays in-row
    }
  } else if (j < 557056u){ src = oWl;  sj = j - 294912u; }
  else if (j < 1605632u){ src = m1Wl; sj = j - 557056u; }
  else                  { src = m2Wl; sj = j - 1605632u; }
  float4 a = ((const float4*)src)[sj];
  float4 b = ((const float4*)src)[sj + 1u];
  *(us8*)&wl[j*4u] = cvt2(a, b);
}

// pairs = (4*2,654,208 + 8,192,000)/2 = 9,404,416 -> 36736 blocks
__global__ __launch_bounds__(256) void k_cvtmega(
    const float* __restrict__ zW, const float* __restrict__ pW,
    const float* __restrict__ oW, const float* __restrict__ m1W,
    const float* __restrict__ m2W, const float* __restrict__ hW,
    ushort* __restrict__ wall, ushort* __restrict__ whb)
{
  u32 ii = blockIdx.x*256u + threadIdx.x;
  if (ii >= 9404416u) return;
  u32 i = ii*2u;
  if (i >= 10616832u){
    u32 j = i - 10616832u;
    float4 a = ((const float4*)hW)[j];
    float4 b = ((const float4*)hW)[j + 1u];
    *(us8*)&whb[j*4u] = cvt2(a, b);
    return;
  }
  u32 l = i / 2654208u;
  u32 j = i - l*2654208u;
  cvt_layer_pair(j, zW + (size_t)l*1048576u, pW + (size_t)l*98304u,
                 oW + (size_t)l*1048576u, m1W + (size_t)l*4194304u,
                 m2W + (size_t)l*4194304u, wall + (size_t)l*10616832u);
}

// per-layer fallback: 1,327,104 pairs -> 5184 blocks
__global__ __launch_bounds__(256) void k_cvtall(
    const float* __restrict__ zWl, const float* __restrict__ pWl,
    const float* __restrict__ oWl, const float* __restrict__ m1Wl,
    const float* __restrict__ m2Wl, ushort* __restrict__ wl)
{
  u32 ii = blockIdx.x*256u + threadIdx.x;
  if (ii >= 1327104u) return;
  cvt_layer_pair(ii*2u, zWl, pWl, oWl, m1Wl, m2Wl, wl);
}

__global__ __launch_bounds__(256) void k_cvt(const float* __restrict__ in, ushort* __restrict__ out, int n4){
  int i = blockIdx.x*256 + threadIdx.x;
  if (i*2 >= n4) return;
  float4 a = ((const float4*)in)[i*2];
  float4 b = ((const float4*)in)[i*2 + 1];
  *(us8*)&out[(size_t)i*8] = cvt2(a, b);
}

// ---------------- time embedding ----------------
__global__ __launch_bounds__(256) void k_temb1m(const int* __restrict__ ts, const float* __restrict__ w1,
                                                const float* __restrict__ b1, float* __restrict__ t1){
  __shared__ float sXT[1024];
  int bid = blockIdx.x;
  int tid = threadIdx.x;
  int b = (bid*4) >> 12;
  float tv = (float)ts[b];
  #pragma unroll
  for (int k=0;k<4;k++){
    int j = tid + k*256;
    int i = j & 511;
    float arg = tv * expf(-(9.210340371976184f/512.f) * (float)i);
    sXT[j] = (j < 512) ? sinf(arg) : cosf(arg);
  }
  __syncthreads();
  int o = bid*4 + (tid >> 6);
  int lane = tid & 63;
  int j = o & 4095;
  const float4* xr = (const float4*)sXT;
  const float4* wr = (const float4*)(w1 + (size_t)j*1024);
  float acc = 0.f;
  #pragma unroll
  for (int i=0;i<4;i++){
    float4 x4 = xr[i*64 + lane], w4 = wr[i*64 + lane];
    acc += x4.x*w4.x + x4.y*w4.y + x4.z*w4.z + x4.w*w4.w;
  }
  #pragma unroll
  for (int off=32; off; off>>=1) acc += __shfl_down(acc, off);
  if (lane==0) t1[o] = silu_f(acc + b1[j]);
}

__global__ __launch_bounds__(256) void k_temb2(const float* __restrict__ t1, const float* __restrict__ w2,
                                               const float* __restrict__ b2, float* __restrict__ t2){
  int o = blockIdx.x*4 + (threadIdx.x >> 6);
  int lane = threadIdx.x & 63;
  int b = o >> 10, j = o & 1023;
  const float4* xr = (const float4*)(t1 + b*4096);
  const float4* wr = (const float4*)(w2 + (size_t)j*4096);
  float acc = 0.f;
  #pragma unroll
  for (int i=0;i<16;i++){
    float4 x4 = xr[i*64 + lane], w4 = wr[i*64 + lane];
    acc += x4.x*w4.x + x4.y*w4.y + x4.z*w4.z + x4.w*w4.w;
  }
  #pragma unroll
  for (int off=32; off; off>>=1) acc += __shfl_down(acc, off);
  if (lane==0) t2[o] = acc + b2[j];
}

// ---------------- layernorm ----------------
DEV void ln_body(float4 v, const float* sc, const float* bi, int row, int t,
                 float* o, ushort* obf)
{
  float sum = v.x+v.y+v.z+v.w;
  float sq  = v.x*v.x+v.y*v.y+v.z*v.z+v.w*v.w;
  for (int o_=32;o_;o_>>=1){ sum += __shfl_down(sum,o_); sq += __shfl_down(sq,o_); }
  __shared__ float ps[8];
  int lane = t & 63, wid = t >> 6;
  if (lane==0){ ps[wid]=sum; ps[4+wid]=sq; }
  __syncthreads();
  float tot = ps[0]+ps[1]+ps[2]+ps[3];
  float tsq = ps[4]+ps[5]+ps[6]+ps[7];
  float m = tot * (1.f/1024.f);
  float var = tsq*(1.f/1024.f) - m*m;
  float r = rsqrtf(var + 1e-5f);
  float4 s4 = ((const float4*)sc)[t];
  float4 b4 = ((const float4*)bi)[t];
  float4 o4;
  o4.x = (v.x-m)*r*s4.x + b4.x;
  o4.y = (v.y-m)*r*s4.y + b4.y;
  o4.z = (v.z-m)*r*s4.z + b4.z;
  o4.w = (v.w-m)*r*s4.w + b4.w;
  ((float4*)(o + (size_t)row*1024))[t] = o4;
  ushort4 ob; ob.x=f2b(o4.x); ob.y=f2b(o4.y); ob.z=f2b(o4.z); ob.w=f2b(o4.w);
  ((ushort4*)(obf + (size_t)row*1024))[t] = ob;
}

__global__ __launch_bounds__(256) void k_ln(const float* __restrict__ x, const float* __restrict__ sc,
                                            const float* __restrict__ bi, float* __restrict__ o,
                                            ushort* __restrict__ obf){
  int row = blockIdx.x, t = threadIdx.x;
  float4 v = ((const float4*)(x + (size_t)row*1024))[t];
  ln_body(v, sc, bi, row, t, o, obf);
}

__global__ __launch_bounds__(256) void k_embln(const int* __restrict__ ids, const float* __restrict__ tok,
                                               const float* __restrict__ t2, const float* __restrict__ sc,
                                               const float* __restrict__ bi, float* __restrict__ xout,
                                               float* __restrict__ o, ushort* __restrict__ obf){
  int row = blockIdx.x, t = threadIdx.x;
  int id = ids[row];
  float4 v = ((const float4*)(tok + (size_t)id*1024))[t];
  float4 e = ((const float4*)(t2 + ((row >> 9) << 10)))[t];
  v.x += e.x; v.y += e.y; v.z += e.z; v.w += e.w;
  ((float4*)(xout + (size_t)row*1024))[t] = v;
  ln_body(v, sc, bi, row, t, o, obf);
}

// ---------------- fused dt + conv + chunk-parallel SSM scan + ypost ----------------
__global__ __launch_bounds__(512) void k_scanf(
    const ushort* __restrict__ pb64, const float* __restrict__ dtW, const float* __restrict__ dtb,
    const float* __restrict__ xn, const float* __restrict__ p, const float* __restrict__ alog,
    const float* __restrict__ z, const float* __restrict__ Dp,
    const float* __restrict__ cw, ushort* __restrict__ y2b)
{
  const int bid = blockIdx.x;
  const int logical = (bid & 7)*256 + (bid >> 3);
  const int d = logical & 1023;
  const int b = logical >> 10;
  const int tid = threadIdx.x;
  const int c = tid >> 4, n = tid & 15;
  const float al = alog[d*16 + n];
  const float A = -expf(al);
  const float invA = 1.f/(A + 1e-10f);
  const bool tiny = fabsf(A) < 1e-8f;
  const float dscale = Dp[d];
  const float cw0 = cw[d*4], cw1 = cw[d*4+1], cw2 = cw[d*4+2], cw3 = cw[d*4+3];
  const size_t base = (size_t)b*512*1024 + d;
  const float* pp = p + (size_t)b*512*96;
  const int s0 = c*16;

  __shared__ float sXN[520];
  __shared__ float sDT[512], sZ[512];
  __shared__ float sA[512], sB[512], sH[512];
  __shared__ float sDTW[64];

  if (tid < 64) sDTW[tid] = dtW[d*64 + tid];
  {
    int s = tid - 3;
    sXN[tid] = (s >= 0) ? xn[base + (size_t)s*1024] : 0.f;
    if (tid < 3) sXN[512 + tid] = xn[base + (size_t)(509 + tid)*1024];
    sZ[tid] = z[base + (size_t)tid*1024];
  }
  __syncthreads();

  {
    const us8* pr = (const us8*)(pb64 + (size_t)(b*512 + tid)*64);
    float acc = 0.f;
    #pragma unroll
    for (int q=0;q<8;q++){
      us8 v = pr[q];
      #pragma unroll
      for (int e=0;e<8;e++)
        acc = fmaf(b2f(v[e]), sDTW[q*8+e], acc);
    }
    sDT[tid] = softplus_f(acc + dtb[d]);
  }
  __syncthreads();

  float At[16], inp[16];
  float h = 0.f, pa = 1.f;
  #pragma unroll
  for (int s8=0; s8<16; s8++){
    int s = s0 + s8;
    float uv = silu_f(sXN[s]*cw0 + sXN[s+1]*cw1 + sXN[s+2]*cw2 + sXN[s+3]*cw3);
    float dtv = sDT[s];
    float Bpv = pp[s*96 + 64 + n];
    float a  = expf(dtv*A);
    float bt = tiny ? dtv : (a-1.f)*invA;
    At[s8] = a;
    float ip = bt*Bpv*uv;
    inp[s8] = ip;
    h = a*h + ip;
    pa *= a;
  }
  sA[tid]=pa; sB[tid]=h;
  __syncthreads();
  if (tid < 16){
    float H = 0.f;
    #pragma unroll
    for (int c2=0;c2<32;c2++){
      sH[c2*16+tid] = H;
      H = sA[c2*16+tid]*H + sB[c2*16+tid];
    }
  }
  __syncthreads();

  h = sH[tid];
  #pragma unroll
  for (int s8=0; s8<16; s8++){
    int s = s0 + s8;
    h = At[s8]*h + inp[s8];
    float Cpv = pp[s*96 + 80 + n];
    float cc = Cpv*h;
    cc += __shfl_xor(cc,1);
    cc += __shfl_xor(cc,2);
    cc += __shfl_xor(cc,4);
    cc += __shfl_xor(cc,8);
    if (n==0){
      float uv = silu_f(sXN[s]*cw0 + sXN[s+1]*cw1 + sXN[s+2]*cw2 + sXN[s+3]*cw3);
      float zv = sZ[s];
      y2b[base + (size_t)s*1024] = f2b((cc + uv*dscale) * (zv/(1.f+expf(-zv))));
    }
  }
}

// ---------------- bf16 MFMA GEMM (TM x TN), gl_lds + XOR swizzle ----------------
template<int TM, int TN, int EPI, bool OBF>
__global__ __launch_bounds__(256) void k_bgemm(
    const ushort* __restrict__ A,
    const ushort* __restrict__ W,
    const float* __restrict__ bias,
    const float* __restrict__ resid,
    void* __restrict__ Cout,
    int ldc, int nmax, int K,
    float* __restrict__ pout, ushort* __restrict__ pbout)
{
  constexpr int WN = 2;
  constexpr int WM = 2;
  constexpr int MR = TM/(WM*16);
  constexpr int NR = TN/(WN*16);

  __shared__ ushort As[TM*64] __attribute__((aligned(16)));
  __shared__ ushort Bs[TN*64] __attribute__((aligned(16)));
  const int t = threadIdx.x;
  const int w = t >> 6, lane = t & 63;
  const int wn = w % WN, wm = w / WN;
  const int m0 = blockIdx.y * TM;
  const int n0 = blockIdx.x * TN;

  f32x4 acc[MR][NR];
  #pragma unroll
  for (int i=0;i<MR;i++)
    #pragma unroll
    for (int j=0;j<NR;j++) acc[i][j] = (f32x4){0.f,0.f,0.f,0.f};

  const int srow = (lane >> 3);
  const int scol = (((lane & 7) ^ srow)) * 8;

  for (int k0 = 0; k0 < K; k0 += 64){
    __syncthreads();
    #pragma unroll
    for (int i=0;i<TM/32;i++){
      int chunk = i*4 + w;
      int row = chunk*8 + srow;
      gl_lds16(A + (size_t)(m0 + row)*K + k0 + scol, &As[chunk*512]);
    }
    #pragma unroll
    for (int i=0;i<TN/32;i++){
      int chunk = i*4 + w;
      int row = chunk*8 + srow;
      gl_lds16(W + (size_t)(n0 + row)*K + k0 + scol, &Bs[chunk*512]);
    }
    __syncthreads();
    const int fr = lane & 15;
    const int hi = lane >> 4;
    #pragma unroll
    for (int kk=0; kk<2; ++kk){
      bf16x8 a[MR], b[NR];
      const int cofs = (((kk<<2) | hi) ^ (fr & 7)) * 8;
      #pragma unroll
      for (int am=0; am<MR; am++)
        a[am] = *(const bf16x8*)&As[(wm*(MR*16) + am*16 + fr)*64 + cofs];
      #pragma unroll
      for (int bn=0; bn<NR; bn++)
        b[bn] = *(const bf16x8*)&Bs[(wn*(NR*16) + bn*16 + fr)*64 + cofs];
      #pragma unroll
      for (int am=0; am<MR; am++)
        #pragma unroll
        for (int bn=0; bn<NR; bn++)
          acc[am][bn] = __builtin_amdgcn_mfma_f32_16x16x32_bf16(a[am], b[bn], acc[am][bn], 0, 0, 0);
    }
  }

  #pragma unroll
  for (int am=0; am<MR; am++){
    #pragma unroll
    for (int bn=0; bn<NR; bn++){
      int r0 = m0 + wm*(MR*16) + am*16 + ((lane>>4)<<2);
      int cc = n0 + wn*(NR*16) + bn*16 + (lane&15);
      if (cc >= nmax) continue;
      float bv = 0.f;
      if constexpr (EPI==1 || EPI==2 || EPI==5) bv = bias[cc];
      #pragma unroll
      for (int r=0; r<4; r++){
        float v = acc[am][bn][r];
        if constexpr (EPI==1 || EPI==2 || EPI==5) v += bv;
        if constexpr (EPI==2) v = gelu_f(v);
        if constexpr (EPI==4 || EPI==5) v += resid[(size_t)(r0+r)*ldc + cc];
        if constexpr (EPI==6){
          if (cc < 1024) ((float*)Cout)[(size_t)(r0+r)*ldc + cc] = v;
          else {
            int pc = cc - 1024;
            if (pc < 96) pout[(size_t)(r0+r)*96 + pc] = v;
            if (pc < 64) pbout[(size_t)(r0+r)*64 + pc] = f2b(v);
          }
        } else if constexpr (OBF){
          ((ushort*)Cout)[(size_t)(r0+r)*ldc + cc] = f2b(v);
        } else {
          ((float*)Cout)[(size_t)(r0+r)*ldc + cc] = v;
        }
      }
    }
  }
}

// ---------------- head GEMM: 256x128 tile, 512 thr / 8 waves, XCD-grouped ----------------
__global__ __launch_bounds__(512) void k_bgemmH(
    const ushort* __restrict__ A,
    const ushort* __restrict__ W,
    const float* __restrict__ bias,
    float* __restrict__ Cout,
    int ldc, int K)
{
  __shared__ ushort As[256*64] __attribute__((aligned(16)));
  __shared__ ushort Bs[128*64] __attribute__((aligned(16)));
  const int t = threadIdx.x;
  const int w = t >> 6, lane = t & 63;
  const int wn = w & 1, wm = w >> 1;
  const int bid = blockIdx.x;
  const int logical = (bid & 7)*125 + (bid >> 3);
  const int m0 = (logical & 3) * 256;
  const int n0 = (logical >> 2) * 128;

  f32x4 acc[4][4];
  #pragma unroll
  for (int i=0;i<4;i++)
    #pragma unroll
    for (int j=0;j<4;j++) acc[i][j] = (f32x4){0.f,0.f,0.f,0.f};

  const int srow = (lane >> 3);
  const int scol = (((lane & 7) ^ srow)) * 8;

  for (int k0 = 0; k0 < K; k0 += 64){
    __syncthreads();
    #pragma unroll
    for (int i=0;i<4;i++){
      int chunk = i*8 + w;
      int row = chunk*8 + srow;
      gl_lds16(A + (size_t)(m0 + row)*K + k0 + scol, &As[chunk*512]);
    }
    #pragma unroll
    for (int i=0;i<2;i++){
      int chunk = i*8 + w;
      int row = chunk*8 + srow;
      gl_lds16(W + (size_t)(n0 + row)*K + k0 + scol, &Bs[chunk*512]);
    }
    __syncthreads();
    const int fr = lane & 15;
    const int hi = lane >> 4;
    #pragma unroll
    for (int kk=0; kk<2; ++kk){
      bf16x8 a[4], b[4];
      const int cofs = (((kk<<2) | hi) ^ (fr & 7)) * 8;
      #pragma unroll
      for (int am=0; am<4; am++)
        a[am] = *(const bf16x8*)&As[(wm*64 + am*16 + fr)*64 + cofs];
      #pragma unroll
      for (int bn=0; bn<4; bn++)
        b[bn] = *(const bf16x8*)&Bs[(wn*64 + bn*16 + fr)*64 + cofs];
      #pragma unroll
      for (int am=0; am<4; am++)
        #pragma unroll
        for (int bn=0; bn<4; bn++)
          acc[am][bn] = __builtin_amdgcn_mfma_f32_16x16x32_bf16(a[am], b[bn], acc[am][bn], 0, 0, 0);
    }
  }

  #pragma unroll
  for (int am=0; am<4; am++){
    #pragma unroll
    for (int bn=0; bn<4; bn++){
      int r0 = m0 + wm*64 + am*16 + ((lane>>4)<<2);
      int cc = n0 + wn*64 + bn*16 + (lane&15);
      float bv = bias[cc];
      #pragma unroll
      for (int r=0; r<4; r++)
        Cout[(size_t)(r0+r)*ldc + cc] = acc[am][bn][r] + bv;
    }
  }
}

extern "C" void kernel_launch(void* const* d_in, const int* in_sizes, int n_in,
                              void* d_out, int out_size, void* d_ws, size_t ws_size,
                              hipStream_t stream)
{
  const int*   ids    = (const int*)d_in[0];
  const int*   tsteps = (const int*)d_in[1];
  const float* tok    = (const float*)d_in[2];
  const float* tw1    = (const float*)d_in[3];
  const float* tb1    = (const float*)d_in[4];
  const float* tw2    = (const float*)d_in[5];
  const float* tb2    = (const float*)d_in[6];
  const float* n1s    = (const float*)d_in[7];
  const float* n1b    = (const float*)d_in[8];
  // d_in[9] = xW, unused by the reference
  const float* zW     = (const float*)d_in[10];
  const float* pW     = (const float*)d_in[11];
  const float* cW     = (const float*)d_in[12];
  const float* dtW    = (const float*)d_in[13];
  const float* dtb    = (const float*)d_in[14];
  const float* alog   = (const float*)d_in[15];
  const float* Dp     = (const float*)d_in[16];
  const float* oW     = (const float*)d_in[17];
  const float* n2s    = (const float*)d_in[18];
  const float* n2b    = (const float*)d_in[19];
  const float* m1W    = (const float*)d_in[20];
  const float* m1b    = (const float*)d_in[21];
  const float* m2W    = (const float*)d_in[22];
  const float* m2b    = (const float*)d_in[23];
  const float* nos    = (const float*)d_in[24];
  const float* nob    = (const float*)d_in[25];
  const float* hW     = (const float*)d_in[26];
  const float* hb     = (const float*)d_in[27];

  float* ws = (float*)d_ws;
  float*  x    = ws;
  float*  xn   = ws + 1048576;
  float*  z    = ws + 2097152;
  float*  p    = ws + 3145728;
  ushort* pb64 = (ushort*)(ws + 3244032);
  float*  t1   = ws + 3276800;
  float*  t2   = ws + 3284992;
  ushort* xnb  = (ushort*)(ws + 3670016);
  ushort* y2b  = (ushort*)(ws + 4194304);
  ushort* h1b  = (ushort*)(ws + 5242880);

  const size_t WBASE = 7340032;
  const size_t WL_US = 10616832;
  const bool big = ws_size >= 179830784ull;
  ushort* wall = (ushort*)(ws + WBASE);
  ushort* whb  = big ? (ushort*)(ws + WBASE + 4*(WL_US/2))
                     : (ushort*)(ws + WBASE);

  dim3 blk(256);
  if (big)
    k_cvtmega<<<dim3(36736), blk, 0, stream>>>(zW, pW, oW, m1W, m2W, hW, wall, whb);
  k_temb1m<<<dim3(2048), blk, 0, stream>>>(tsteps, tw1, tb1, t1);
  k_temb2<<<dim3(512),  blk, 0, stream>>>(t1, tw2, tb2, t2);

  for (int l=0; l<4; l++){
    ushort* wl = wall + (big ? (size_t)l*WL_US : 0);
    ushort* wzp = wl;
    ushort* wo  = wl + 1179648;
    ushort* wm1 = wl + 2228224;
    ushort* wm2 = wl + 6422528;
    if (!big)
      k_cvtall<<<dim3(5184), blk, 0, stream>>>(
          zW + (size_t)l*1048576, pW + (size_t)l*98304, oW + (size_t)l*1048576,
          m1W + (size_t)l*4194304, m2W + (size_t)l*4194304, wl);
    if (l == 0)
      k_embln<<<dim3(1024), blk, 0, stream>>>(ids, tok, t2, n1s, n1b, x, xn, xnb);
    else
      k_ln<<<dim3(1024), blk, 0, stream>>>(x, n1s + l*1024, n1b + l*1024, xn, xnb);
    // z | p | pb64 in one GEMM (N=1152 packed), 64x64 tiles: 288 blocks
    k_bgemm<64,64,6,false><<<dim3(18,16), blk, 0, stream>>>(xnb, wzp, nullptr, nullptr, z,
                                                            1024, 1152, 1024, p, pb64);
    k_scanf<<<dim3(2048), dim3(512), 0, stream>>>(pb64, dtW + (size_t)l*65536, dtb + l*1024,
                                                  xn, p, alog + l*16384, z, Dp + l*1024,
                                                  cW + l*4096, y2b);
    // x += y2 @ oW^T   (64x64 tiles: 256 blocks)
    k_bgemm<64,64,4,false><<<dim3(16,16), blk, 0, stream>>>(y2b, wo, nullptr, x, x,
                                                            1024, 1024, 1024, nullptr, nullptr);
    k_ln<<<dim3(1024), blk, 0, stream>>>(x, n2s + l*1024, n2b + l*1024, xn, xnb);
    // m1 (N=4096): 64x64 tiles -> 1024 blocks (4/CU)
    k_bgemm<64,64,2,true><<<dim3(64,16), blk, 0, stream>>>(xnb, wm1, m1b + l*4096, nullptr, h1b,
                                                           4096, 4096, 1024, nullptr, nullptr);
    // m2 (K=4096), 64x64 tiles: 256 blocks
    k_bgemm<64,64,5,false><<<dim3(16,16), blk, 0, stream>>>(h1b, wm2, m2b + l*1024, x, x,
                                                            1024, 1024, 4096, nullptr, nullptr);
  }
  k_ln<<<dim3(1024), blk, 0, stream>>>(x, nos, nob, xn, xnb);

  if (big){
    k_bgemmH<<<dim3(1000), dim3(512), 0, stream>>>(xnb, whb, hb, (float*)d_out, 32000, 1024);
  } else {
    for (int h=0; h<2; h++){
      k_cvt<<<dim3(8000), blk, 0, stream>>>(hW + (size_t)h*16384000, whb, 8192000);
      k_bgemm<128,128,1,false><<<dim3(125,8), blk, 0, stream>>>(xnb, whb, hb + h*16000, nullptr,
                                                                (float*)d_out + h*16000,
                                                                32000, 16000, 1024, nullptr, nullptr);
    }
  }
}

// Round 15
// 890.940 us; speedup vs baseline: 1.2553x; 1.1022x over previous
//
#include <hip/hip_runtime.h>
#include <math.h>

// HydraScaleLM forward. Round 15:
//  - head GEMM -> k_bgemmHF: reads fp32 hW directly, pipelined reg-staged B
//    (cvt in staging, XOR-swizzled ds_writes, vmcnt(4)-counted barrier keeps
//    prefetch in flight across MFMA phase). Head chunk removed from cvtmega.
//  - cvtmega: layer-only, reverted to round-13 single-unit form (fastest).
// All else = round 14 (64x64 layer GEMMs incl. m1, XOR-swizzle, fused scanf).
// Shapes: B=2, S=512, D=1024, DEPTH=4, N=16, K=4, R=64, MLP=4096, V=32000. M=1024.

#define DEV __device__ __forceinline__
typedef unsigned int u32;
typedef unsigned short ushort;
typedef __bf16 bf16x8 __attribute__((ext_vector_type(8)));
typedef float f32x4 __attribute__((ext_vector_type(4)));
typedef ushort us8 __attribute__((ext_vector_type(8)));

DEV float silu_f(float x){ return x / (1.f + expf(-x)); }
DEV float gelu_f(float x){ return 0.5f * x * (1.f + erff(x * 0.70710678118654752f)); }
DEV float softplus_f(float x){ return (x > 20.f) ? x : log1pf(expf(x)); }
DEV ushort f2b(float f){
  u32 u = __builtin_bit_cast(u32, f);
  return (ushort)((u + 0x7fffu + ((u >> 16) & 1u)) >> 16);
}
DEV float b2f(ushort u){ return __builtin_bit_cast(float, (u32)u << 16); }

DEV void gl_lds16(const ushort* g, ushort* l){
  __builtin_amdgcn_global_load_lds(
      (const __attribute__((address_space(1))) u32*)g,
      (__attribute__((address_space(3))) u32*)l, 16, 0, 0);
}

DEV us8 cvt2(float4 a, float4 b){
  us8 v;
  v[0]=f2b(a.x); v[1]=f2b(a.y); v[2]=f2b(a.z); v[3]=f2b(a.w);
  v[4]=f2b(b.x); v[5]=f2b(b.y); v[6]=f2b(b.z); v[7]=f2b(b.w);
  return v;
}

// ---------------- weight conversion (layer weights only; single-unit) ----------------
DEV void cvt_layer_unit(u32 j, const float* zWl, const float* pWl, const float* oWl,
                        const float* m1Wl, const float* m2Wl, ushort* wl)
{
  const float* src; u32 sj, dj;
  if (j < 294912u){
    dj = j;
    u32 row = j >> 8;
    if (row < 1024u){ src = zWl; sj = j; }
    else {
      u32 pr = row - 1024u;
      if (pr >= 96u){ ushort4 z4 = {0,0,0,0}; ((ushort4*)wl)[dj] = z4; return; }
      src = pWl; sj = pr*256u + (j & 255u);
    }
  } else if (j < 557056u){ u32 k = j - 294912u;  dj = j; src = oWl;  sj = k; }
  else if (j < 1605632u){ u32 k = j - 557056u;  dj = j; src = m1Wl; sj = k; }
  else                  { u32 k = j - 1605632u; dj = j; src = m2Wl; sj = k; }
  float4 v = ((const float4*)src)[sj];
  ushort4 o4; o4.x=f2b(v.x); o4.y=f2b(v.y); o4.z=f2b(v.z); o4.w=f2b(v.w);
  ((ushort4*)wl)[dj] = o4;
}

// 4 layers only: units = 4*2,654,208 = 10,616,832 -> 41472 blocks
__global__ __launch_bounds__(256) void k_cvtmega(
    const float* __restrict__ zW, const float* __restrict__ pW,
    const float* __restrict__ oW, const float* __restrict__ m1W,
    const float* __restrict__ m2W, ushort* __restrict__ wall)
{
  u32 i = blockIdx.x*256u + threadIdx.x;
  if (i >= 10616832u) return;
  u32 l = i / 2654208u;
  u32 j = i - l*2654208u;
  cvt_layer_unit(j, zW + (size_t)l*1048576u, pW + (size_t)l*98304u,
                 oW + (size_t)l*1048576u, m1W + (size_t)l*4194304u,
                 m2W + (size_t)l*4194304u, wall + (size_t)l*10616832u);
}

__global__ __launch_bounds__(256) void k_cvtall(
    const float* __restrict__ zWl, const float* __restrict__ pWl,
    const float* __restrict__ oWl, const float* __restrict__ m1Wl,
    const float* __restrict__ m2Wl, ushort* __restrict__ wl)
{
  u32 j = blockIdx.x*256u + threadIdx.x;
  if (j >= 2654208u) return;
  cvt_layer_unit(j, zWl, pWl, oWl, m1Wl, m2Wl, wl);
}

__global__ __launch_bounds__(256) void k_cvt(const float* __restrict__ in, ushort* __restrict__ out, int n4){
  int i = blockIdx.x*256 + threadIdx.x;
  if (i >= n4) return;
  float4 v = ((const float4*)in)[i];
  ushort4 o; o.x=f2b(v.x); o.y=f2b(v.y); o.z=f2b(v.z); o.w=f2b(v.w);
  ((ushort4*)out)[i] = o;
}

// ---------------- time embedding ----------------
__global__ __launch_bounds__(256) void k_temb1m(const int* __restrict__ ts, const float* __restrict__ w1,
                                                const float* __restrict__ b1, float* __restrict__ t1){
  __shared__ float sXT[1024];
  int bid = blockIdx.x;
  int tid = threadIdx.x;
  int b = (bid*4) >> 12;
  float tv = (float)ts[b];
  #pragma unroll
  for (int k=0;k<4;k++){
    int j = tid + k*256;
    int i = j & 511;
    float arg = tv * expf(-(9.210340371976184f/512.f) * (float)i);
    sXT[j] = (j < 512) ? sinf(arg) : cosf(arg);
  }
  __syncthreads();
  int o = bid*4 + (tid >> 6);
  int lane = tid & 63;
  int j = o & 4095;
  const float4* xr = (const float4*)sXT;
  const float4* wr = (const float4*)(w1 + (size_t)j*1024);
  float acc = 0.f;
  #pragma unroll
  for (int i=0;i<4;i++){
    float4 x4 = xr[i*64 + lane], w4 = wr[i*64 + lane];
    acc += x4.x*w4.x + x4.y*w4.y + x4.z*w4.z + x4.w*w4.w;
  }
  #pragma unroll
  for (int off=32; off; off>>=1) acc += __shfl_down(acc, off);
  if (lane==0) t1[o] = silu_f(acc + b1[j]);
}

__global__ __launch_bounds__(256) void k_temb2(const float* __restrict__ t1, const float* __restrict__ w2,
                                               const float* __restrict__ b2, float* __restrict__ t2){
  int o = blockIdx.x*4 + (threadIdx.x >> 6);
  int lane = threadIdx.x & 63;
  int b = o >> 10, j = o & 1023;
  const float4* xr = (const float4*)(t1 + b*4096);
  const float4* wr = (const float4*)(w2 + (size_t)j*4096);
  float acc = 0.f;
  #pragma unroll
  for (int i=0;i<16;i++){
    float4 x4 = xr[i*64 + lane], w4 = wr[i*64 + lane];
    acc += x4.x*w4.x + x4.y*w4.y + x4.z*w4.z + x4.w*w4.w;
  }
  #pragma unroll
  for (int off=32; off; off>>=1) acc += __shfl_down(acc, off);
  if (lane==0) t2[o] = acc + b2[j];
}

// ---------------- layernorm ----------------
DEV void ln_body(float4 v, const float* sc, const float* bi, int row, int t,
                 float* o, ushort* obf)
{
  float sum = v.x+v.y+v.z+v.w;
  float sq  = v.x*v.x+v.y*v.y+v.z*v.z+v.w*v.w;
  for (int o_=32;o_;o_>>=1){ sum += __shfl_down(sum,o_); sq += __shfl_down(sq,o_); }
  __shared__ float ps[8];
  int lane = t & 63, wid = t >> 6;
  if (lane==0){ ps[wid]=sum; ps[4+wid]=sq; }
  __syncthreads();
  float tot = ps[0]+ps[1]+ps[2]+ps[3];
  float tsq = ps[4]+ps[5]+ps[6]+ps[7];
  float m = tot * (1.f/1024.f);
  float var = tsq*(1.f/1024.f) - m*m;
  float r = rsqrtf(var + 1e-5f);
  float4 s4 = ((const float4*)sc)[t];
  float4 b4 = ((const float4*)bi)[t];
  float4 o4;
  o4.x = (v.x-m)*r*s4.x + b4.x;
  o4.y = (v.y-m)*r*s4.y + b4.y;
  o4.z = (v.z-m)*r*s4.z + b4.z;
  o4.w = (v.w-m)*r*s4.w + b4.w;
  ((float4*)(o + (size_t)row*1024))[t] = o4;
  ushort4 ob; ob.x=f2b(o4.x); ob.y=f2b(o4.y); ob.z=f2b(o4.z); ob.w=f2b(o4.w);
  ((ushort4*)(obf + (size_t)row*1024))[t] = ob;
}

__global__ __launch_bounds__(256) void k_ln(const float* __restrict__ x, const float* __restrict__ sc,
                                            const float* __restrict__ bi, float* __restrict__ o,
                                            ushort* __restrict__ obf){
  int row = blockIdx.x, t = threadIdx.x;
  float4 v = ((const float4*)(x + (size_t)row*1024))[t];
  ln_body(v, sc, bi, row, t, o, obf);
}

__global__ __launch_bounds__(256) void k_embln(const int* __restrict__ ids, const float* __restrict__ tok,
                                               const float* __restrict__ t2, const float* __restrict__ sc,
                                               const float* __restrict__ bi, float* __restrict__ xout,
                                               float* __restrict__ o, ushort* __restrict__ obf){
  int row = blockIdx.x, t = threadIdx.x;
  int id = ids[row];
  float4 v = ((const float4*)(tok + (size_t)id*1024))[t];
  float4 e = ((const float4*)(t2 + ((row >> 9) << 10)))[t];
  v.x += e.x; v.y += e.y; v.z += e.z; v.w += e.w;
  ((float4*)(xout + (size_t)row*1024))[t] = v;
  ln_body(v, sc, bi, row, t, o, obf);
}

// ---------------- fused dt + conv + chunk-parallel SSM scan + ypost ----------------
__global__ __launch_bounds__(512) void k_scanf(
    const ushort* __restrict__ pb64, const float* __restrict__ dtW, const float* __restrict__ dtb,
    const float* __restrict__ xn, const float* __restrict__ p, const float* __restrict__ alog,
    const float* __restrict__ z, const float* __restrict__ Dp,
    const float* __restrict__ cw, ushort* __restrict__ y2b)
{
  const int bid = blockIdx.x;
  const int logical = (bid & 7)*256 + (bid >> 3);
  const int d = logical & 1023;
  const int b = logical >> 10;
  const int tid = threadIdx.x;
  const int c = tid >> 4, n = tid & 15;
  const float al = alog[d*16 + n];
  const float A = -expf(al);
  const float invA = 1.f/(A + 1e-10f);
  const bool tiny = fabsf(A) < 1e-8f;
  const float dscale = Dp[d];
  const float cw0 = cw[d*4], cw1 = cw[d*4+1], cw2 = cw[d*4+2], cw3 = cw[d*4+3];
  const size_t base = (size_t)b*512*1024 + d;
  const float* pp = p + (size_t)b*512*96;
  const int s0 = c*16;

  __shared__ float sXN[520];
  __shared__ float sDT[512], sZ[512];
  __shared__ float sA[512], sB[512], sH[512];
  __shared__ float sDTW[64];

  if (tid < 64) sDTW[tid] = dtW[d*64 + tid];
  {
    int s = tid - 3;
    sXN[tid] = (s >= 0) ? xn[base + (size_t)s*1024] : 0.f;
    if (tid < 3) sXN[512 + tid] = xn[base + (size_t)(509 + tid)*1024];
    sZ[tid] = z[base + (size_t)tid*1024];
  }
  __syncthreads();

  {
    const us8* pr = (const us8*)(pb64 + (size_t)(b*512 + tid)*64);
    float acc = 0.f;
    #pragma unroll
    for (int q=0;q<8;q++){
      us8 v = pr[q];
      #pragma unroll
      for (int e=0;e<8;e++)
        acc = fmaf(b2f(v[e]), sDTW[q*8+e], acc);
    }
    sDT[tid] = softplus_f(acc + dtb[d]);
  }
  __syncthreads();

  float At[16], inp[16];
  float h = 0.f, pa = 1.f;
  #pragma unroll
  for (int s8=0; s8<16; s8++){
    int s = s0 + s8;
    float uv = silu_f(sXN[s]*cw0 + sXN[s+1]*cw1 + sXN[s+2]*cw2 + sXN[s+3]*cw3);
    float dtv = sDT[s];
    float Bpv = pp[s*96 + 64 + n];
    float a  = expf(dtv*A);
    float bt = tiny ? dtv : (a-1.f)*invA;
    At[s8] = a;
    float ip = bt*Bpv*uv;
    inp[s8] = ip;
    h = a*h + ip;
    pa *= a;
  }
  sA[tid]=pa; sB[tid]=h;
  __syncthreads();
  if (tid < 16){
    float H = 0.f;
    #pragma unroll
    for (int c2=0;c2<32;c2++){
      sH[c2*16+tid] = H;
      H = sA[c2*16+tid]*H + sB[c2*16+tid];
    }
  }
  __syncthreads();

  h = sH[tid];
  #pragma unroll
  for (int s8=0; s8<16; s8++){
    int s = s0 + s8;
    h = At[s8]*h + inp[s8];
    float Cpv = pp[s*96 + 80 + n];
    float cc = Cpv*h;
    cc += __shfl_xor(cc,1);
    cc += __shfl_xor(cc,2);
    cc += __shfl_xor(cc,4);
    cc += __shfl_xor(cc,8);
    if (n==0){
      float uv = silu_f(sXN[s]*cw0 + sXN[s+1]*cw1 + sXN[s+2]*cw2 + sXN[s+3]*cw3);
      float zv = sZ[s];
      y2b[base + (size_t)s*1024] = f2b((cc + uv*dscale) * (zv/(1.f+expf(-zv))));
    }
  }
}

// ---------------- bf16 MFMA GEMM (TM x TN), gl_lds + XOR swizzle ----------------
template<int TM, int TN, int EPI, bool OBF>
__global__ __launch_bounds__(256) void k_bgemm(
    const ushort* __restrict__ A,
    const ushort* __restrict__ W,
    const float* __restrict__ bias,
    const float* __restrict__ resid,
    void* __restrict__ Cout,
    int ldc, int nmax, int K,
    float* __restrict__ pout, ushort* __restrict__ pbout)
{
  constexpr int WN = 2;
  constexpr int WM = 2;
  constexpr int MR = TM/(WM*16);
  constexpr int NR = TN/(WN*16);

  __shared__ ushort As[TM*64] __attribute__((aligned(16)));
  __shared__ ushort Bs[TN*64] __attribute__((aligned(16)));
  const int t = threadIdx.x;
  const int w = t >> 6, lane = t & 63;
  const int wn = w % WN, wm = w / WN;
  const int m0 = blockIdx.y * TM;
  const int n0 = blockIdx.x * TN;

  f32x4 acc[MR][NR];
  #pragma unroll
  for (int i=0;i<MR;i++)
    #pragma unroll
    for (int j=0;j<NR;j++) acc[i][j] = (f32x4){0.f,0.f,0.f,0.f};

  const int srow = (lane >> 3);
  const int scol = (((lane & 7) ^ srow)) * 8;

  for (int k0 = 0; k0 < K; k0 += 64){
    __syncthreads();
    #pragma unroll
    for (int i=0;i<TM/32;i++){
      int chunk = i*4 + w;
      int row = chunk*8 + srow;
      gl_lds16(A + (size_t)(m0 + row)*K + k0 + scol, &As[chunk*512]);
    }
    #pragma unroll
    for (int i=0;i<TN/32;i++){
      int chunk = i*4 + w;
      int row = chunk*8 + srow;
      gl_lds16(W + (size_t)(n0 + row)*K + k0 + scol, &Bs[chunk*512]);
    }
    __syncthreads();
    const int fr = lane & 15;
    const int hi = lane >> 4;
    #pragma unroll
    for (int kk=0; kk<2; ++kk){
      bf16x8 a[MR], b[NR];
      const int cofs = (((kk<<2) | hi) ^ (fr & 7)) * 8;
      #pragma unroll
      for (int am=0; am<MR; am++)
        a[am] = *(const bf16x8*)&As[(wm*(MR*16) + am*16 + fr)*64 + cofs];
      #pragma unroll
      for (int bn=0; bn<NR; bn++)
        b[bn] = *(const bf16x8*)&Bs[(wn*(NR*16) + bn*16 + fr)*64 + cofs];
      #pragma unroll
      for (int am=0; am<MR; am++)
        #pragma unroll
        for (int bn=0; bn<NR; bn++)
          acc[am][bn] = __builtin_amdgcn_mfma_f32_16x16x32_bf16(a[am], b[bn], acc[am][bn], 0, 0, 0);
    }
  }

  #pragma unroll
  for (int am=0; am<MR; am++){
    #pragma unroll
    for (int bn=0; bn<NR; bn++){
      int r0 = m0 + wm*(MR*16) + am*16 + ((lane>>4)<<2);
      int cc = n0 + wn*(NR*16) + bn*16 + (lane&15);
      if (cc >= nmax) continue;
      float bv = 0.f;
      if constexpr (EPI==1 || EPI==2 || EPI==5) bv = bias[cc];
      #pragma unroll
      for (int r=0; r<4; r++){
        float v = acc[am][bn][r];
        if constexpr (EPI==1 || EPI==2 || EPI==5) v += bv;
        if constexpr (EPI==2) v = gelu_f(v);
        if constexpr (EPI==4 || EPI==5) v += resid[(size_t)(r0+r)*ldc + cc];
        if constexpr (EPI==6){
          if (cc < 1024) ((float*)Cout)[(size_t)(r0+r)*ldc + cc] = v;
          else {
            int pc = cc - 1024;
            if (pc < 96) pout[(size_t)(r0+r)*96 + pc] = v;
            if (pc < 64) pbout[(size_t)(r0+r)*64 + pc] = f2b(v);
          }
        } else if constexpr (OBF){
          ((ushort*)Cout)[(size_t)(r0+r)*ldc + cc] = f2b(v);
        } else {
          ((float*)Cout)[(size_t)(r0+r)*ldc + cc] = v;
        }
      }
    }
  }
}

// ---------------- head GEMM, fp32 W: 256x128 tile, 512 thr / 8 waves ----------------
// A (bf16) via gl_lds with inverse-swizzled source; B (fp32) reg-staged:
// cvt2 -> ds_write at swizzled slot (slot ^ (row&7)) -> same read contract.
// Pipeline: prefetch next fb issued before a counted vmcnt(4) barrier, so the
// 4 B-loads stay in flight across the MFMA phase (drained by next top sync).
__global__ __launch_bounds__(512) void k_bgemmHF(
    const ushort* __restrict__ A,
    const float*  __restrict__ W,
    const float* __restrict__ bias,
    float* __restrict__ Cout,
    int ldc, int K)
{
  __shared__ ushort As[256*64] __attribute__((aligned(16)));   // 32 KB
  __shared__ ushort Bs[128*64] __attribute__((aligned(16)));   // 16 KB
  const int t = threadIdx.x;
  const int w = t >> 6, lane = t & 63;
  const int wn = w & 1, wm = w >> 1;             // 2 x 4 waves
  const int bid = blockIdx.x;                    // 0..999
  const int logical = (bid & 7)*125 + (bid >> 3);
  const int m0 = (logical & 3) * 256;
  const int n0 = (logical >> 2) * 128;

  f32x4 acc[4][4];
  #pragma unroll
  for (int i=0;i<4;i++)
    #pragma unroll
    for (int j=0;j<4;j++) acc[i][j] = (f32x4){0.f,0.f,0.f,0.f};

  const int srow = (lane >> 3);
  const int scolA = (((lane & 7) ^ srow)) * 8;

  // B staging: thread owns row t>>2 (0..127), fp32 cols (t&3)*16..+15
  const int brow = t >> 2;
  const int bq   = t & 3;
  const float* wp = W + (size_t)(n0 + brow)*K + bq*16;
  const int slot0 = ((bq*2)   ^ (brow & 7)) * 8;
  const int slot1 = ((bq*2+1) ^ (brow & 7)) * 8;

  float4 fb[4];
  #pragma unroll
  for (int j=0;j<4;j++) fb[j] = *(const float4*)(wp + j*4);

  for (int k0 = 0; k0 < K; k0 += 64){
    __syncthreads();                              // drains prefetch; LDS free
    #pragma unroll
    for (int i=0;i<4;i++){                        // A: 32 chunks / 8 waves
      int chunk = i*8 + w;
      int row = chunk*8 + srow;
      gl_lds16(A + (size_t)(m0 + row)*K + k0 + scolA, &As[chunk*512]);
    }
    // B: cvt + swizzled ds_write
    *(us8*)&Bs[brow*64 + slot0] = cvt2(fb[0], fb[1]);
    *(us8*)&Bs[brow*64 + slot1] = cvt2(fb[2], fb[3]);
    // prefetch next B tile; stays in flight across MFMA phase
    if (k0 + 64 < K){
      #pragma unroll
      for (int j=0;j<4;j++) fb[j] = *(const float4*)(wp + k0 + 64 + j*4);
      asm volatile("s_waitcnt vmcnt(4) lgkmcnt(0)" ::: "memory");  // A done, writes done
    } else {
      asm volatile("s_waitcnt vmcnt(0) lgkmcnt(0)" ::: "memory");
    }
    __builtin_amdgcn_sched_barrier(0);
    __builtin_amdgcn_s_barrier();
    __builtin_amdgcn_sched_barrier(0);
    const int fr = lane & 15;
    const int hi = lane >> 4;
    #pragma unroll
    for (int kk=0; kk<2; ++kk){
      bf16x8 a[4], b[4];
      const int cofs = (((kk<<2) | hi) ^ (fr & 7)) * 8;
      #pragma unroll
      for (int am=0; am<4; am++)
        a[am] = *(const bf16x8*)&As[(wm*64 + am*16 + fr)*64 + cofs];
      #pragma unroll
      for (int bn=0; bn<4; bn++)
        b[bn] = *(const bf16x8*)&Bs[(wn*64 + bn*16 + fr)*64 + cofs];
      #pragma unroll
      for (int am=0; am<4; am++)
        #pragma unroll
        for (int bn=0; bn<4; bn++)
          acc[am][bn] = __builtin_amdgcn_mfma_f32_16x16x32_bf16(a[am], b[bn], acc[am][bn], 0, 0, 0);
    }
  }

  #pragma unroll
  for (int am=0; am<4; am++){
    #pragma unroll
    for (int bn=0; bn<4; bn++){
      int r0 = m0 + wm*64 + am*16 + ((lane>>4)<<2);
      int cc = n0 + wn*64 + bn*16 + (lane&15);
      float bv = bias[cc];
      #pragma unroll
      for (int r=0; r<4; r++)
        Cout[(size_t)(r0+r)*ldc + cc] = acc[am][bn][r] + bv;
    }
  }
}

extern "C" void kernel_launch(void* const* d_in, const int* in_sizes, int n_in,
                              void* d_out, int out_size, void* d_ws, size_t ws_size,
                              hipStream_t stream)
{
  const int*   ids    = (const int*)d_in[0];
  const int*   tsteps = (const int*)d_in[1];
  const float* tok    = (const float*)d_in[2];
  const float* tw1    = (const float*)d_in[3];
  const float* tb1    = (const float*)d_in[4];
  const float* tw2    = (const float*)d_in[5];
  const float* tb2    = (const float*)d_in[6];
  const float* n1s    = (const float*)d_in[7];
  const float* n1b    = (const float*)d_in[8];
  // d_in[9] = xW, unused by the reference
  const float* zW     = (const float*)d_in[10];
  const float* pW     = (const float*)d_in[11];
  const float* cW     = (const float*)d_in[12];
  const float* dtW    = (const float*)d_in[13];
  const float* dtb    = (const float*)d_in[14];
  const float* alog   = (const float*)d_in[15];
  const float* Dp     = (const float*)d_in[16];
  const float* oW     = (const float*)d_in[17];
  const float* n2s    = (const float*)d_in[18];
  const float* n2b    = (const float*)d_in[19];
  const float* m1W    = (const float*)d_in[20];
  const float* m1b    = (const float*)d_in[21];
  const float* m2W    = (const float*)d_in[22];
  const float* m2b    = (const float*)d_in[23];
  const float* nos    = (const float*)d_in[24];
  const float* nob    = (const float*)d_in[25];
  const float* hW     = (const float*)d_in[26];
  const float* hb     = (const float*)d_in[27];

  float* ws = (float*)d_ws;
  float*  x    = ws;
  float*  xn   = ws + 1048576;
  float*  z    = ws + 2097152;
  float*  p    = ws + 3145728;
  ushort* pb64 = (ushort*)(ws + 3244032);
  float*  t1   = ws + 3276800;
  float*  t2   = ws + 3284992;
  ushort* xnb  = (ushort*)(ws + 3670016);
  ushort* y2b  = (ushort*)(ws + 4194304);
  ushort* h1b  = (ushort*)(ws + 5242880);

  const size_t WBASE = 7340032;
  const size_t WL_US = 10616832;
  const bool big = ws_size >= 179830784ull;
  ushort* wall = (ushort*)(ws + WBASE);
  ushort* whb  = (ushort*)(ws + WBASE + (big ? 4*(WL_US/2) : 0));   // only used in !big

  dim3 blk(256);
  if (big)
    k_cvtmega<<<dim3(41472), blk, 0, stream>>>(zW, pW, oW, m1W, m2W, wall);
  k_temb1m<<<dim3(2048), blk, 0, stream>>>(tsteps, tw1, tb1, t1);
  k_temb2<<<dim3(512),  blk, 0, stream>>>(t1, tw2, tb2, t2);

  for (int l=0; l<4; l++){
    ushort* wl = wall + (big ? (size_t)l*WL_US : 0);
    ushort* wzp = wl;
    ushort* wo  = wl + 1179648;
    ushort* wm1 = wl + 2228224;
    ushort* wm2 = wl + 6422528;
    if (!big)
      k_cvtall<<<dim3(10368), blk, 0, stream>>>(
          zW + (size_t)l*1048576, pW + (size_t)l*98304, oW + (size_t)l*1048576,
          m1W + (size_t)l*4194304, m2W + (size_t)l*4194304, wl);
    if (l == 0)
      k_embln<<<dim3(1024), blk, 0, stream>>>(ids, tok, t2, n1s, n1b, x, xn, xnb);
    else
      k_ln<<<dim3(1024), blk, 0, stream>>>(x, n1s + l*1024, n1b + l*1024, xn, xnb);
    // z | p | pb64 in one GEMM (N=1152 packed), 64x64 tiles: 288 blocks
    k_bgemm<64,64,6,false><<<dim3(18,16), blk, 0, stream>>>(xnb, wzp, nullptr, nullptr, z,
                                                            1024, 1152, 1024, p, pb64);
    k_scanf<<<dim3(2048), dim3(512), 0, stream>>>(pb64, dtW + (size_t)l*65536, dtb + l*1024,
                                                  xn, p, alog + l*16384, z, Dp + l*1024,
                                                  cW + l*4096, y2b);
    // x += y2 @ oW^T   (64x64 tiles: 256 blocks)
    k_bgemm<64,64,4,false><<<dim3(16,16), blk, 0, stream>>>(y2b, wo, nullptr, x, x,
                                                            1024, 1024, 1024, nullptr, nullptr);
    k_ln<<<dim3(1024), blk, 0, stream>>>(x, n2s + l*1024, n2b + l*1024, xn, xnb);
    // m1 (N=4096): 64x64 tiles -> 1024 blocks
    k_bgemm<64,64,2,true><<<dim3(64,16), blk, 0, stream>>>(xnb, wm1, m1b + l*4096, nullptr, h1b,
                                                           4096, 4096, 1024, nullptr, nullptr);
    // m2 (K=4096), 64x64 tiles: 256 blocks
    k_bgemm<64,64,5,false><<<dim3(16,16), blk, 0, stream>>>(h1b, wm2, m2b + l*1024, x, x,
                                                            1024, 1024, 4096, nullptr, nullptr);
  }
  k_ln<<<dim3(1024), blk, 0, stream>>>(x, nos, nob, xn, xnb);

  if (big){
    // head: fp32 W direct (no conversion pass)
    k_bgemmHF<<<dim3(1000), dim3(512), 0, stream>>>(xnb, hW, hb, (float*)d_out, 32000, 1024);
  } else {
    for (int h=0; h<2; h++){
      k_cvt<<<dim3(16000), blk, 0, stream>>>(hW + (size_t)h*16384000, whb, 4096000);
      k_bgemm<128,128,1,false><<<dim3(125,8), blk, 0, stream>>>(xnb, whb, hb + h*16000, nullptr,
                                                                (float*)d_out + h*16000,
                                                                32000, 16000, 1024, nullptr, nullptr);
    }
  }
}

// Round 16
// 879.309 us; speedup vs baseline: 1.2719x; 1.0132x over previous
//
#include <hip/hip_runtime.h>
#include <math.h>

// HydraScaleLM forward. Round 16: k_bgemm -> double-buffered LDS with counted
// vmcnt(4) + raw s_barrier (no full drain in K-loop). Prologue loads tile 0;
// per step: issue tile k+1 into other buf, wait only current tile, barrier,
// MFMA, barrier. All else = round 15 (bgemmHF head, fused scanf, cvtmega).
// Shapes: B=2, S=512, D=1024, DEPTH=4, N=16, K=4, R=64, MLP=4096, V=32000. M=1024.

#define DEV __device__ __forceinline__
typedef unsigned int u32;
typedef unsigned short ushort;
typedef __bf16 bf16x8 __attribute__((ext_vector_type(8)));
typedef float f32x4 __attribute__((ext_vector_type(4)));
typedef ushort us8 __attribute__((ext_vector_type(8)));

DEV float silu_f(float x){ return x / (1.f + expf(-x)); }
DEV float gelu_f(float x){ return 0.5f * x * (1.f + erff(x * 0.70710678118654752f)); }
DEV float softplus_f(float x){ return (x > 20.f) ? x : log1pf(expf(x)); }
DEV ushort f2b(float f){
  u32 u = __builtin_bit_cast(u32, f);
  return (ushort)((u + 0x7fffu + ((u >> 16) & 1u)) >> 16);
}
DEV float b2f(ushort u){ return __builtin_bit_cast(float, (u32)u << 16); }

DEV void gl_lds16(const ushort* g, ushort* l){
  __builtin_amdgcn_global_load_lds(
      (const __attribute__((address_space(1))) u32*)g,
      (__attribute__((address_space(3))) u32*)l, 16, 0, 0);
}

DEV us8 cvt2(float4 a, float4 b){
  us8 v;
  v[0]=f2b(a.x); v[1]=f2b(a.y); v[2]=f2b(a.z); v[3]=f2b(a.w);
  v[4]=f2b(b.x); v[5]=f2b(b.y); v[6]=f2b(b.z); v[7]=f2b(b.w);
  return v;
}

// ---------------- weight conversion (layer weights only) ----------------
DEV void cvt_layer_unit(u32 j, const float* zWl, const float* pWl, const float* oWl,
                        const float* m1Wl, const float* m2Wl, ushort* wl)
{
  const float* src; u32 sj, dj;
  if (j < 294912u){
    dj = j;
    u32 row = j >> 8;
    if (row < 1024u){ src = zWl; sj = j; }
    else {
      u32 pr = row - 1024u;
      if (pr >= 96u){ ushort4 z4 = {0,0,0,0}; ((ushort4*)wl)[dj] = z4; return; }
      src = pWl; sj = pr*256u + (j & 255u);
    }
  } else if (j < 557056u){ u32 k = j - 294912u;  dj = j; src = oWl;  sj = k; }
  else if (j < 1605632u){ u32 k = j - 557056u;  dj = j; src = m1Wl; sj = k; }
  else                  { u32 k = j - 1605632u; dj = j; src = m2Wl; sj = k; }
  float4 v = ((const float4*)src)[sj];
  ushort4 o4; o4.x=f2b(v.x); o4.y=f2b(v.y); o4.z=f2b(v.z); o4.w=f2b(v.w);
  ((ushort4*)wl)[dj] = o4;
}

__global__ __launch_bounds__(256) void k_cvtmega(
    const float* __restrict__ zW, const float* __restrict__ pW,
    const float* __restrict__ oW, const float* __restrict__ m1W,
    const float* __restrict__ m2W, ushort* __restrict__ wall)
{
  u32 i = blockIdx.x*256u + threadIdx.x;
  if (i >= 10616832u) return;
  u32 l = i / 2654208u;
  u32 j = i - l*2654208u;
  cvt_layer_unit(j, zW + (size_t)l*1048576u, pW + (size_t)l*98304u,
                 oW + (size_t)l*1048576u, m1W + (size_t)l*4194304u,
                 m2W + (size_t)l*4194304u, wall + (size_t)l*10616832u);
}

__global__ __launch_bounds__(256) void k_cvtall(
    const float* __restrict__ zWl, const float* __restrict__ pWl,
    const float* __restrict__ oWl, const float* __restrict__ m1Wl,
    const float* __restrict__ m2Wl, ushort* __restrict__ wl)
{
  u32 j = blockIdx.x*256u + threadIdx.x;
  if (j >= 2654208u) return;
  cvt_layer_unit(j, zWl, pWl, oWl, m1Wl, m2Wl, wl);
}

__global__ __launch_bounds__(256) void k_cvt(const float* __restrict__ in, ushort* __restrict__ out, int n4){
  int i = blockIdx.x*256 + threadIdx.x;
  if (i >= n4) return;
  float4 v = ((const float4*)in)[i];
  ushort4 o; o.x=f2b(v.x); o.y=f2b(v.y); o.z=f2b(v.z); o.w=f2b(v.w);
  ((ushort4*)out)[i] = o;
}

// ---------------- time embedding ----------------
__global__ __launch_bounds__(256) void k_temb1m(const int* __restrict__ ts, const float* __restrict__ w1,
                                                const float* __restrict__ b1, float* __restrict__ t1){
  __shared__ float sXT[1024];
  int bid = blockIdx.x;
  int tid = threadIdx.x;
  int b = (bid*4) >> 12;
  float tv = (float)ts[b];
  #pragma unroll
  for (int k=0;k<4;k++){
    int j = tid + k*256;
    int i = j & 511;
    float arg = tv * expf(-(9.210340371976184f/512.f) * (float)i);
    sXT[j] = (j < 512) ? sinf(arg) : cosf(arg);
  }
  __syncthreads();
  int o = bid*4 + (tid >> 6);
  int lane = tid & 63;
  int j = o & 4095;
  const float4* xr = (const float4*)sXT;
  const float4* wr = (const float4*)(w1 + (size_t)j*1024);
  float acc = 0.f;
  #pragma unroll
  for (int i=0;i<4;i++){
    float4 x4 = xr[i*64 + lane], w4 = wr[i*64 + lane];
    acc += x4.x*w4.x + x4.y*w4.y + x4.z*w4.z + x4.w*w4.w;
  }
  #pragma unroll
  for (int off=32; off; off>>=1) acc += __shfl_down(acc, off);
  if (lane==0) t1[o] = silu_f(acc + b1[j]);
}

__global__ __launch_bounds__(256) void k_temb2(const float* __restrict__ t1, const float* __restrict__ w2,
                                               const float* __restrict__ b2, float* __restrict__ t2){
  int o = blockIdx.x*4 + (threadIdx.x >> 6);
  int lane = threadIdx.x & 63;
  int b = o >> 10, j = o & 1023;
  const float4* xr = (const float4*)(t1 + b*4096);
  const float4* wr = (const float4*)(w2 + (size_t)j*4096);
  float acc = 0.f;
  #pragma unroll
  for (int i=0;i<16;i++){
    float4 x4 = xr[i*64 + lane], w4 = wr[i*64 + lane];
    acc += x4.x*w4.x + x4.y*w4.y + x4.z*w4.z + x4.w*w4.w;
  }
  #pragma unroll
  for (int off=32; off; off>>=1) acc += __shfl_down(acc, off);
  if (lane==0) t2[o] = acc + b2[j];
}

// ---------------- layernorm ----------------
DEV void ln_body(float4 v, const float* sc, const float* bi, int row, int t,
                 float* o, ushort* obf)
{
  float sum = v.x+v.y+v.z+v.w;
  float sq  = v.x*v.x+v.y*v.y+v.z*v.z+v.w*v.w;
  for (int o_=32;o_;o_>>=1){ sum += __shfl_down(sum,o_); sq += __shfl_down(sq,o_); }
  __shared__ float ps[8];
  int lane = t & 63, wid = t >> 6;
  if (lane==0){ ps[wid]=sum; ps[4+wid]=sq; }
  __syncthreads();
  float tot = ps[0]+ps[1]+ps[2]+ps[3];
  float tsq = ps[4]+ps[5]+ps[6]+ps[7];
  float m = tot * (1.f/1024.f);
  float var = tsq*(1.f/1024.f) - m*m;
  float r = rsqrtf(var + 1e-5f);
  float4 s4 = ((const float4*)sc)[t];
  float4 b4 = ((const float4*)bi)[t];
  float4 o4;
  o4.x = (v.x-m)*r*s4.x + b4.x;
  o4.y = (v.y-m)*r*s4.y + b4.y;
  o4.z = (v.z-m)*r*s4.z + b4.z;
  o4.w = (v.w-m)*r*s4.w + b4.w;
  ((float4*)(o + (size_t)row*1024))[t] = o4;
  ushort4 ob; ob.x=f2b(o4.x); ob.y=f2b(o4.y); ob.z=f2b(o4.z); ob.w=f2b(o4.w);
  ((ushort4*)(obf + (size_t)row*1024))[t] = ob;
}

__global__ __launch_bounds__(256) void k_ln(const float* __restrict__ x, const float* __restrict__ sc,
                                            const float* __restrict__ bi, float* __restrict__ o,
                                            ushort* __restrict__ obf){
  int row = blockIdx.x, t = threadIdx.x;
  float4 v = ((const float4*)(x + (size_t)row*1024))[t];
  ln_body(v, sc, bi, row, t, o, obf);
}

__global__ __launch_bounds__(256) void k_embln(const int* __restrict__ ids, const float* __restrict__ tok,
                                               const float* __restrict__ t2, const float* __restrict__ sc,
                                               const float* __restrict__ bi, float* __restrict__ xout,
                                               float* __restrict__ o, ushort* __restrict__ obf){
  int row = blockIdx.x, t = threadIdx.x;
  int id = ids[row];
  float4 v = ((const float4*)(tok + (size_t)id*1024))[t];
  float4 e = ((const float4*)(t2 + ((row >> 9) << 10)))[t];
  v.x += e.x; v.y += e.y; v.z += e.z; v.w += e.w;
  ((float4*)(xout + (size_t)row*1024))[t] = v;
  ln_body(v, sc, bi, row, t, o, obf);
}

// ---------------- fused dt + conv + chunk-parallel SSM scan + ypost ----------------
__global__ __launch_bounds__(512) void k_scanf(
    const ushort* __restrict__ pb64, const float* __restrict__ dtW, const float* __restrict__ dtb,
    const float* __restrict__ xn, const float* __restrict__ p, const float* __restrict__ alog,
    const float* __restrict__ z, const float* __restrict__ Dp,
    const float* __restrict__ cw, ushort* __restrict__ y2b)
{
  const int bid = blockIdx.x;
  const int logical = (bid & 7)*256 + (bid >> 3);
  const int d = logical & 1023;
  const int b = logical >> 10;
  const int tid = threadIdx.x;
  const int c = tid >> 4, n = tid & 15;
  const float al = alog[d*16 + n];
  const float A = -expf(al);
  const float invA = 1.f/(A + 1e-10f);
  const bool tiny = fabsf(A) < 1e-8f;
  const float dscale = Dp[d];
  const float cw0 = cw[d*4], cw1 = cw[d*4+1], cw2 = cw[d*4+2], cw3 = cw[d*4+3];
  const size_t base = (size_t)b*512*1024 + d;
  const float* pp = p + (size_t)b*512*96;
  const int s0 = c*16;

  __shared__ float sXN[520];
  __shared__ float sDT[512], sZ[512];
  __shared__ float sA[512], sB[512], sH[512];
  __shared__ float sDTW[64];

  if (tid < 64) sDTW[tid] = dtW[d*64 + tid];
  {
    int s = tid - 3;
    sXN[tid] = (s >= 0) ? xn[base + (size_t)s*1024] : 0.f;
    if (tid < 3) sXN[512 + tid] = xn[base + (size_t)(509 + tid)*1024];
    sZ[tid] = z[base + (size_t)tid*1024];
  }
  __syncthreads();

  {
    const us8* pr = (const us8*)(pb64 + (size_t)(b*512 + tid)*64);
    float acc = 0.f;
    #pragma unroll
    for (int q=0;q<8;q++){
      us8 v = pr[q];
      #pragma unroll
      for (int e=0;e<8;e++)
        acc = fmaf(b2f(v[e]), sDTW[q*8+e], acc);
    }
    sDT[tid] = softplus_f(acc + dtb[d]);
  }
  __syncthreads();

  float At[16], inp[16];
  float h = 0.f, pa = 1.f;
  #pragma unroll
  for (int s8=0; s8<16; s8++){
    int s = s0 + s8;
    float uv = silu_f(sXN[s]*cw0 + sXN[s+1]*cw1 + sXN[s+2]*cw2 + sXN[s+3]*cw3);
    float dtv = sDT[s];
    float Bpv = pp[s*96 + 64 + n];
    float a  = expf(dtv*A);
    float bt = tiny ? dtv : (a-1.f)*invA;
    At[s8] = a;
    float ip = bt*Bpv*uv;
    inp[s8] = ip;
    h = a*h + ip;
    pa *= a;
  }
  sA[tid]=pa; sB[tid]=h;
  __syncthreads();
  if (tid < 16){
    float H = 0.f;
    #pragma unroll
    for (int c2=0;c2<32;c2++){
      sH[c2*16+tid] = H;
      H = sA[c2*16+tid]*H + sB[c2*16+tid];
    }
  }
  __syncthreads();

  h = sH[tid];
  #pragma unroll
  for (int s8=0; s8<16; s8++){
    int s = s0 + s8;
    h = At[s8]*h + inp[s8];
    float Cpv = pp[s*96 + 80 + n];
    float cc = Cpv*h;
    cc += __shfl_xor(cc,1);
    cc += __shfl_xor(cc,2);
    cc += __shfl_xor(cc,4);
    cc += __shfl_xor(cc,8);
    if (n==0){
      float uv = silu_f(sXN[s]*cw0 + sXN[s+1]*cw1 + sXN[s+2]*cw2 + sXN[s+3]*cw3);
      float zv = sZ[s];
      y2b[base + (size_t)s*1024] = f2b((cc + uv*dscale) * (zv/(1.f+expf(-zv))));
    }
  }
}

// ---------------- bf16 MFMA GEMM (TM x TN), double-buffered counted-vmcnt ----------------
// Per step: issue tile k+1 into other buf -> vmcnt(LT) (current tile done,
// next in flight) -> raw barrier -> MFMA cur -> raw barrier. No full drain.
template<int TM, int TN, int EPI, bool OBF>
__global__ __launch_bounds__(256) void k_bgemm(
    const ushort* __restrict__ A,
    const ushort* __restrict__ W,
    const float* __restrict__ bias,
    const float* __restrict__ resid,
    void* __restrict__ Cout,
    int ldc, int nmax, int K,
    float* __restrict__ pout, ushort* __restrict__ pbout)
{
  constexpr int WN = 2;
  constexpr int WM = 2;
  constexpr int MR = TM/(WM*16);
  constexpr int NR = TN/(WN*16);
  constexpr int LA = TM/32;          // gl_lds per wave (A)
  constexpr int LB = TN/32;          // gl_lds per wave (B)
  constexpr int LT = LA + LB;

  __shared__ ushort As[2][TM*64] __attribute__((aligned(16)));
  __shared__ ushort Bs[2][TN*64] __attribute__((aligned(16)));
  const int t = threadIdx.x;
  const int w = t >> 6, lane = t & 63;
  const int wn = w % WN, wm = w / WN;
  const int m0 = blockIdx.y * TM;
  const int n0 = blockIdx.x * TN;

  f32x4 acc[MR][NR];
  #pragma unroll
  for (int i=0;i<MR;i++)
    #pragma unroll
    for (int j=0;j<NR;j++) acc[i][j] = (f32x4){0.f,0.f,0.f,0.f};

  const int srow = (lane >> 3);
  const int scol = (((lane & 7) ^ srow)) * 8;

  auto issue = [&](int k0, int buf){
    #pragma unroll
    for (int i=0;i<LA;i++){
      int chunk = i*4 + w;
      int row = chunk*8 + srow;
      gl_lds16(A + (size_t)(m0 + row)*K + k0 + scol, &As[buf][chunk*512]);
    }
    #pragma unroll
    for (int i=0;i<LB;i++){
      int chunk = i*4 + w;
      int row = chunk*8 + srow;
      gl_lds16(W + (size_t)(n0 + row)*K + k0 + scol, &Bs[buf][chunk*512]);
    }
  };

  issue(0, 0);
  const int NS = K >> 6;
  const int fr = lane & 15;
  const int hi = lane >> 4;
  for (int s = 0; s < NS; ++s){
    const int cur = s & 1;
    if (s + 1 < NS){
      issue((s+1)*64, cur^1);
      asm volatile("s_waitcnt vmcnt(%0)" :: "i"(LT) : "memory");
    } else {
      asm volatile("s_waitcnt vmcnt(0)" ::: "memory");
    }
    __builtin_amdgcn_sched_barrier(0);
    __builtin_amdgcn_s_barrier();
    __builtin_amdgcn_sched_barrier(0);
    #pragma unroll
    for (int kk=0; kk<2; ++kk){
      bf16x8 a[MR], b[NR];
      const int cofs = (((kk<<2) | hi) ^ (fr & 7)) * 8;
      #pragma unroll
      for (int am=0; am<MR; am++)
        a[am] = *(const bf16x8*)&As[cur][(wm*(MR*16) + am*16 + fr)*64 + cofs];
      #pragma unroll
      for (int bn=0; bn<NR; bn++)
        b[bn] = *(const bf16x8*)&Bs[cur][(wn*(NR*16) + bn*16 + fr)*64 + cofs];
      #pragma unroll
      for (int am=0; am<MR; am++)
        #pragma unroll
        for (int bn=0; bn<NR; bn++)
          acc[am][bn] = __builtin_amdgcn_mfma_f32_16x16x32_bf16(a[am], b[bn], acc[am][bn], 0, 0, 0);
    }
    __builtin_amdgcn_sched_barrier(0);
    __builtin_amdgcn_s_barrier();   // all waves done reading buf cur before overwrite
  }

  #pragma unroll
  for (int am=0; am<MR; am++){
    #pragma unroll
    for (int bn=0; bn<NR; bn++){
      int r0 = m0 + wm*(MR*16) + am*16 + ((lane>>4)<<2);
      int cc = n0 + wn*(NR*16) + bn*16 + (lane&15);
      if (cc >= nmax) continue;
      float bv = 0.f;
      if constexpr (EPI==1 || EPI==2 || EPI==5) bv = bias[cc];
      #pragma unroll
      for (int r=0; r<4; r++){
        float v = acc[am][bn][r];
        if constexpr (EPI==1 || EPI==2 || EPI==5) v += bv;
        if constexpr (EPI==2) v = gelu_f(v);
        if constexpr (EPI==4 || EPI==5) v += resid[(size_t)(r0+r)*ldc + cc];
        if constexpr (EPI==6){
          if (cc < 1024) ((float*)Cout)[(size_t)(r0+r)*ldc + cc] = v;
          else {
            int pc = cc - 1024;
            if (pc < 96) pout[(size_t)(r0+r)*96 + pc] = v;
            if (pc < 64) pbout[(size_t)(r0+r)*64 + pc] = f2b(v);
          }
        } else if constexpr (OBF){
          ((ushort*)Cout)[(size_t)(r0+r)*ldc + cc] = f2b(v);
        } else {
          ((float*)Cout)[(size_t)(r0+r)*ldc + cc] = v;
        }
      }
    }
  }
}

// ---------------- head GEMM, fp32 W: 256x128 tile, 512 thr / 8 waves ----------------
__global__ __launch_bounds__(512) void k_bgemmHF(
    const ushort* __restrict__ A,
    const float*  __restrict__ W,
    const float* __restrict__ bias,
    float* __restrict__ Cout,
    int ldc, int K)
{
  __shared__ ushort As[256*64] __attribute__((aligned(16)));
  __shared__ ushort Bs[128*64] __attribute__((aligned(16)));
  const int t = threadIdx.x;
  const int w = t >> 6, lane = t & 63;
  const int wn = w & 1, wm = w >> 1;
  const int bid = blockIdx.x;
  const int logical = (bid & 7)*125 + (bid >> 3);
  const int m0 = (logical & 3) * 256;
  const int n0 = (logical >> 2) * 128;

  f32x4 acc[4][4];
  #pragma unroll
  for (int i=0;i<4;i++)
    #pragma unroll
    for (int j=0;j<4;j++) acc[i][j] = (f32x4){0.f,0.f,0.f,0.f};

  const int srow = (lane >> 3);
  const int scolA = (((lane & 7) ^ srow)) * 8;

  const int brow = t >> 2;
  const int bq   = t & 3;
  const float* wp = W + (size_t)(n0 + brow)*K + bq*16;
  const int slot0 = ((bq*2)   ^ (brow & 7)) * 8;
  const int slot1 = ((bq*2+1) ^ (brow & 7)) * 8;

  float4 fb[4];
  #pragma unroll
  for (int j=0;j<4;j++) fb[j] = *(const float4*)(wp + j*4);

  for (int k0 = 0; k0 < K; k0 += 64){
    __syncthreads();
    #pragma unroll
    for (int i=0;i<4;i++){
      int chunk = i*8 + w;
      int row = chunk*8 + srow;
      gl_lds16(A + (size_t)(m0 + row)*K + k0 + scolA, &As[chunk*512]);
    }
    *(us8*)&Bs[brow*64 + slot0] = cvt2(fb[0], fb[1]);
    *(us8*)&Bs[brow*64 + slot1] = cvt2(fb[2], fb[3]);
    if (k0 + 64 < K){
      #pragma unroll
      for (int j=0;j<4;j++) fb[j] = *(const float4*)(wp + k0 + 64 + j*4);
      asm volatile("s_waitcnt vmcnt(4) lgkmcnt(0)" ::: "memory");
    } else {
      asm volatile("s_waitcnt vmcnt(0) lgkmcnt(0)" ::: "memory");
    }
    __builtin_amdgcn_sched_barrier(0);
    __builtin_amdgcn_s_barrier();
    __builtin_amdgcn_sched_barrier(0);
    const int fr = lane & 15;
    const int hi = lane >> 4;
    #pragma unroll
    for (int kk=0; kk<2; ++kk){
      bf16x8 a[4], b[4];
      const int cofs = (((kk<<2) | hi) ^ (fr & 7)) * 8;
      #pragma unroll
      for (int am=0; am<4; am++)
        a[am] = *(const bf16x8*)&As[(wm*64 + am*16 + fr)*64 + cofs];
      #pragma unroll
      for (int bn=0; bn<4; bn++)
        b[bn] = *(const bf16x8*)&Bs[(wn*64 + bn*16 + fr)*64 + cofs];
      #pragma unroll
      for (int am=0; am<4; am++)
        #pragma unroll
        for (int bn=0; bn<4; bn++)
          acc[am][bn] = __builtin_amdgcn_mfma_f32_16x16x32_bf16(a[am], b[bn], acc[am][bn], 0, 0, 0);
    }
  }

  #pragma unroll
  for (int am=0; am<4; am++){
    #pragma unroll
    for (int bn=0; bn<4; bn++){
      int r0 = m0 + wm*64 + am*16 + ((lane>>4)<<2);
      int cc = n0 + wn*64 + bn*16 + (lane&15);
      float bv = bias[cc];
      #pragma unroll
      for (int r=0; r<4; r++)
        Cout[(size_t)(r0+r)*ldc + cc] = acc[am][bn][r] + bv;
    }
  }
}

extern "C" void kernel_launch(void* const* d_in, const int* in_sizes, int n_in,
                              void* d_out, int out_size, void* d_ws, size_t ws_size,
                              hipStream_t stream)
{
  const int*   ids    = (const int*)d_in[0];
  const int*   tsteps = (const int*)d_in[1];
  const float* tok    = (const float*)d_in[2];
  const float* tw1    = (const float*)d_in[3];
  const float* tb1    = (const float*)d_in[4];
  const float* tw2    = (const float*)d_in[5];
  const float* tb2    = (const float*)d_in[6];
  const float* n1s    = (const float*)d_in[7];
  const float* n1b    = (const float*)d_in[8];
  // d_in[9] = xW, unused by the reference
  const float* zW     = (const float*)d_in[10];
  const float* pW     = (const float*)d_in[11];
  const float* cW     = (const float*)d_in[12];
  const float* dtW    = (const float*)d_in[13];
  const float* dtb    = (const float*)d_in[14];
  const float* alog   = (const float*)d_in[15];
  const float* Dp     = (const float*)d_in[16];
  const float* oW     = (const float*)d_in[17];
  const float* n2s    = (const float*)d_in[18];
  const float* n2b    = (const float*)d_in[19];
  const float* m1W    = (const float*)d_in[20];
  const float* m1b    = (const float*)d_in[21];
  const float* m2W    = (const float*)d_in[22];
  const float* m2b    = (const float*)d_in[23];
  const float* nos    = (const float*)d_in[24];
  const float* nob    = (const float*)d_in[25];
  const float* hW     = (const float*)d_in[26];
  const float* hb     = (const float*)d_in[27];

  float* ws = (float*)d_ws;
  float*  x    = ws;
  float*  xn   = ws + 1048576;
  float*  z    = ws + 2097152;
  float*  p    = ws + 3145728;
  ushort* pb64 = (ushort*)(ws + 3244032);
  float*  t1   = ws + 3276800;
  float*  t2   = ws + 3284992;
  ushort* xnb  = (ushort*)(ws + 3670016);
  ushort* y2b  = (ushort*)(ws + 4194304);
  ushort* h1b  = (ushort*)(ws + 5242880);

  const size_t WBASE = 7340032;
  const size_t WL_US = 10616832;
  const bool big = ws_size >= 179830784ull;
  ushort* wall = (ushort*)(ws + WBASE);
  ushort* whb  = (ushort*)(ws + WBASE + (big ? 4*(WL_US/2) : 0));

  dim3 blk(256);
  if (big)
    k_cvtmega<<<dim3(41472), blk, 0, stream>>>(zW, pW, oW, m1W, m2W, wall);
  k_temb1m<<<dim3(2048), blk, 0, stream>>>(tsteps, tw1, tb1, t1);
  k_temb2<<<dim3(512),  blk, 0, stream>>>(t1, tw2, tb2, t2);

  for (int l=0; l<4; l++){
    ushort* wl = wall + (big ? (size_t)l*WL_US : 0);
    ushort* wzp = wl;
    ushort* wo  = wl + 1179648;
    ushort* wm1 = wl + 2228224;
    ushort* wm2 = wl + 6422528;
    if (!big)
      k_cvtall<<<dim3(10368), blk, 0, stream>>>(
          zW + (size_t)l*1048576, pW + (size_t)l*98304, oW + (size_t)l*1048576,
          m1W + (size_t)l*4194304, m2W + (size_t)l*4194304, wl);
    if (l == 0)
      k_embln<<<dim3(1024), blk, 0, stream>>>(ids, tok, t2, n1s, n1b, x, xn, xnb);
    else
      k_ln<<<dim3(1024), blk, 0, stream>>>(x, n1s + l*1024, n1b + l*1024, xn, xnb);
    // z | p | pb64 in one GEMM (N=1152 packed), 64x64 tiles: 288 blocks
    k_bgemm<64,64,6,false><<<dim3(18,16), blk, 0, stream>>>(xnb, wzp, nullptr, nullptr, z,
                                                            1024, 1152, 1024, p, pb64);
    k_scanf<<<dim3(2048), dim3(512), 0, stream>>>(pb64, dtW + (size_t)l*65536, dtb + l*1024,
                                                  xn, p, alog + l*16384, z, Dp + l*1024,
                                                  cW + l*4096, y2b);
    // x += y2 @ oW^T
    k_bgemm<64,64,4,false><<<dim3(16,16), blk, 0, stream>>>(y2b, wo, nullptr, x, x,
                                                            1024, 1024, 1024, nullptr, nullptr);
    k_ln<<<dim3(1024), blk, 0, stream>>>(x, n2s + l*1024, n2b + l*1024, xn, xnb);
    // m1 (N=4096): 1024 blocks
    k_bgemm<64,64,2,true><<<dim3(64,16), blk, 0, stream>>>(xnb, wm1, m1b + l*4096, nullptr, h1b,
                                                           4096, 4096, 1024, nullptr, nullptr);
    // m2 (K=4096)
    k_bgemm<64,64,5,false><<<dim3(16,16), blk, 0, stream>>>(h1b, wm2, m2b + l*1024, x, x,
                                                            1024, 1024, 4096, nullptr, nullptr);
  }
  k_ln<<<dim3(1024), blk, 0, stream>>>(x, nos, nob, xn, xnb);

  if (big){
    k_bgemmHF<<<dim3(1000), dim3(512), 0, stream>>>(xnb, hW, hb, (float*)d_out, 32000, 1024);
  } else {
    for (int h=0; h<2; h++){
      k_cvt<<<dim3(16000), blk, 0, stream>>>(hW + (size_t)h*16384000, whb, 4096000);
      k_bgemm<128,128,1,false><<<dim3(125,8), blk, 0, stream>>>(xnb, whb, hb + h*16000, nullptr,
                                                                (float*)d_out + h*16000,
                                                                32000, 16000, 1024, nullptr, nullptr);
    }
  }
}

// Round 17
// 872.032 us; speedup vs baseline: 1.2825x; 1.0083x over previous
//
#include <hip/hip_runtime.h>
#include <math.h>

// HydraScaleLM forward. Round 17:
//  - k_bgemmHF: top __syncthreads -> raw s_barrier (the implicit vmcnt(0) drain
//    was killing the B prefetch before A-issue); explicit vmcnt(4) before the
//    ds_write validates B(s) regs; B(s+1) now flies across the whole step.
//  - T5 s_setprio(1) around MFMA clusters in k_bgemm and k_bgemmHF.
// All else = round 16.
// Shapes: B=2, S=512, D=1024, DEPTH=4, N=16, K=4, R=64, MLP=4096, V=32000. M=1024.

#define DEV __device__ __forceinline__
typedef unsigned int u32;
typedef unsigned short ushort;
typedef __bf16 bf16x8 __attribute__((ext_vector_type(8)));
typedef float f32x4 __attribute__((ext_vector_type(4)));
typedef ushort us8 __attribute__((ext_vector_type(8)));

DEV float silu_f(float x){ return x / (1.f + expf(-x)); }
DEV float gelu_f(float x){ return 0.5f * x * (1.f + erff(x * 0.70710678118654752f)); }
DEV float softplus_f(float x){ return (x > 20.f) ? x : log1pf(expf(x)); }
DEV ushort f2b(float f){
  u32 u = __builtin_bit_cast(u32, f);
  return (ushort)((u + 0x7fffu + ((u >> 16) & 1u)) >> 16);
}
DEV float b2f(ushort u){ return __builtin_bit_cast(float, (u32)u << 16); }

DEV void gl_lds16(const ushort* g, ushort* l){
  __builtin_amdgcn_global_load_lds(
      (const __attribute__((address_space(1))) u32*)g,
      (__attribute__((address_space(3))) u32*)l, 16, 0, 0);
}

DEV us8 cvt2(float4 a, float4 b){
  us8 v;
  v[0]=f2b(a.x); v[1]=f2b(a.y); v[2]=f2b(a.z); v[3]=f2b(a.w);
  v[4]=f2b(b.x); v[5]=f2b(b.y); v[6]=f2b(b.z); v[7]=f2b(b.w);
  return v;
}

// ---------------- weight conversion (layer weights only) ----------------
DEV void cvt_layer_unit(u32 j, const float* zWl, const float* pWl, const float* oWl,
                        const float* m1Wl, const float* m2Wl, ushort* wl)
{
  const float* src; u32 sj, dj;
  if (j < 294912u){
    dj = j;
    u32 row = j >> 8;
    if (row < 1024u){ src = zWl; sj = j; }
    else {
      u32 pr = row - 1024u;
      if (pr >= 96u){ ushort4 z4 = {0,0,0,0}; ((ushort4*)wl)[dj] = z4; return; }
      src = pWl; sj = pr*256u + (j & 255u);
    }
  } else if (j < 557056u){ u32 k = j - 294912u;  dj = j; src = oWl;  sj = k; }
  else if (j < 1605632u){ u32 k = j - 557056u;  dj = j; src = m1Wl; sj = k; }
  else                  { u32 k = j - 1605632u; dj = j; src = m2Wl; sj = k; }
  float4 v = ((const float4*)src)[sj];
  ushort4 o4; o4.x=f2b(v.x); o4.y=f2b(v.y); o4.z=f2b(v.z); o4.w=f2b(v.w);
  ((ushort4*)wl)[dj] = o4;
}

__global__ __launch_bounds__(256) void k_cvtmega(
    const float* __restrict__ zW, const float* __restrict__ pW,
    const float* __restrict__ oW, const float* __restrict__ m1W,
    const float* __restrict__ m2W, ushort* __restrict__ wall)
{
  u32 i = blockIdx.x*256u + threadIdx.x;
  if (i >= 10616832u) return;
  u32 l = i / 2654208u;
  u32 j = i - l*2654208u;
  cvt_layer_unit(j, zW + (size_t)l*1048576u, pW + (size_t)l*98304u,
                 oW + (size_t)l*1048576u, m1W + (size_t)l*4194304u,
                 m2W + (size_t)l*4194304u, wall + (size_t)l*10616832u);
}

__global__ __launch_bounds__(256) void k_cvtall(
    const float* __restrict__ zWl, const float* __restrict__ pWl,
    const float* __restrict__ oWl, const float* __restrict__ m1Wl,
    const float* __restrict__ m2Wl, ushort* __restrict__ wl)
{
  u32 j = blockIdx.x*256u + threadIdx.x;
  if (j >= 2654208u) return;
  cvt_layer_unit(j, zWl, pWl, oWl, m1Wl, m2Wl, wl);
}

__global__ __launch_bounds__(256) void k_cvt(const float* __restrict__ in, ushort* __restrict__ out, int n4){
  int i = blockIdx.x*256 + threadIdx.x;
  if (i >= n4) return;
  float4 v = ((const float4*)in)[i];
  ushort4 o; o.x=f2b(v.x); o.y=f2b(v.y); o.z=f2b(v.z); o.w=f2b(v.w);
  ((ushort4*)out)[i] = o;
}

// ---------------- time embedding ----------------
__global__ __launch_bounds__(256) void k_temb1m(const int* __restrict__ ts, const float* __restrict__ w1,
                                                const float* __restrict__ b1, float* __restrict__ t1){
  __shared__ float sXT[1024];
  int bid = blockIdx.x;
  int tid = threadIdx.x;
  int b = (bid*4) >> 12;
  float tv = (float)ts[b];
  #pragma unroll
  for (int k=0;k<4;k++){
    int j = tid + k*256;
    int i = j & 511;
    float arg = tv * expf(-(9.210340371976184f/512.f) * (float)i);
    sXT[j] = (j < 512) ? sinf(arg) : cosf(arg);
  }
  __syncthreads();
  int o = bid*4 + (tid >> 6);
  int lane = tid & 63;
  int j = o & 4095;
  const float4* xr = (const float4*)sXT;
  const float4* wr = (const float4*)(w1 + (size_t)j*1024);
  float acc = 0.f;
  #pragma unroll
  for (int i=0;i<4;i++){
    float4 x4 = xr[i*64 + lane], w4 = wr[i*64 + lane];
    acc += x4.x*w4.x + x4.y*w4.y + x4.z*w4.z + x4.w*w4.w;
  }
  #pragma unroll
  for (int off=32; off; off>>=1) acc += __shfl_down(acc, off);
  if (lane==0) t1[o] = silu_f(acc + b1[j]);
}

__global__ __launch_bounds__(256) void k_temb2(const float* __restrict__ t1, const float* __restrict__ w2,
                                               const float* __restrict__ b2, float* __restrict__ t2){
  int o = blockIdx.x*4 + (threadIdx.x >> 6);
  int lane = threadIdx.x & 63;
  int b = o >> 10, j = o & 1023;
  const float4* xr = (const float4*)(t1 + b*4096);
  const float4* wr = (const float4*)(w2 + (size_t)j*4096);
  float acc = 0.f;
  #pragma unroll
  for (int i=0;i<16;i++){
    float4 x4 = xr[i*64 + lane], w4 = wr[i*64 + lane];
    acc += x4.x*w4.x + x4.y*w4.y + x4.z*w4.z + x4.w*w4.w;
  }
  #pragma unroll
  for (int off=32; off; off>>=1) acc += __shfl_down(acc, off);
  if (lane==0) t2[o] = acc + b2[j];
}

// ---------------- layernorm ----------------
DEV void ln_body(float4 v, const float* sc, const float* bi, int row, int t,
                 float* o, ushort* obf)
{
  float sum = v.x+v.y+v.z+v.w;
  float sq  = v.x*v.x+v.y*v.y+v.z*v.z+v.w*v.w;
  for (int o_=32;o_;o_>>=1){ sum += __shfl_down(sum,o_); sq += __shfl_down(sq,o_); }
  __shared__ float ps[8];
  int lane = t & 63, wid = t >> 6;
  if (lane==0){ ps[wid]=sum; ps[4+wid]=sq; }
  __syncthreads();
  float tot = ps[0]+ps[1]+ps[2]+ps[3];
  float tsq = ps[4]+ps[5]+ps[6]+ps[7];
  float m = tot * (1.f/1024.f);
  float var = tsq*(1.f/1024.f) - m*m;
  float r = rsqrtf(var + 1e-5f);
  float4 s4 = ((const float4*)sc)[t];
  float4 b4 = ((const float4*)bi)[t];
  float4 o4;
  o4.x = (v.x-m)*r*s4.x + b4.x;
  o4.y = (v.y-m)*r*s4.y + b4.y;
  o4.z = (v.z-m)*r*s4.z + b4.z;
  o4.w = (v.w-m)*r*s4.w + b4.w;
  ((float4*)(o + (size_t)row*1024))[t] = o4;
  ushort4 ob; ob.x=f2b(o4.x); ob.y=f2b(o4.y); ob.z=f2b(o4.z); ob.w=f2b(o4.w);
  ((ushort4*)(obf + (size_t)row*1024))[t] = ob;
}

__global__ __launch_bounds__(256) void k_ln(const float* __restrict__ x, const float* __restrict__ sc,
                                            const float* __restrict__ bi, float* __restrict__ o,
                                            ushort* __restrict__ obf){
  int row = blockIdx.x, t = threadIdx.x;
  float4 v = ((const float4*)(x + (size_t)row*1024))[t];
  ln_body(v, sc, bi, row, t, o, obf);
}

__global__ __launch_bounds__(256) void k_embln(const int* __restrict__ ids, const float* __restrict__ tok,
                                               const float* __restrict__ t2, const float* __restrict__ sc,
                                               const float* __restrict__ bi, float* __restrict__ xout,
                                               float* __restrict__ o, ushort* __restrict__ obf){
  int row = blockIdx.x, t = threadIdx.x;
  int id = ids[row];
  float4 v = ((const float4*)(tok + (size_t)id*1024))[t];
  float4 e = ((const float4*)(t2 + ((row >> 9) << 10)))[t];
  v.x += e.x; v.y += e.y; v.z += e.z; v.w += e.w;
  ((float4*)(xout + (size_t)row*1024))[t] = v;
  ln_body(v, sc, bi, row, t, o, obf);
}

// ---------------- fused dt + conv + chunk-parallel SSM scan + ypost ----------------
__global__ __launch_bounds__(512) void k_scanf(
    const ushort* __restrict__ pb64, const float* __restrict__ dtW, const float* __restrict__ dtb,
    const float* __restrict__ xn, const float* __restrict__ p, const float* __restrict__ alog,
    const float* __restrict__ z, const float* __restrict__ Dp,
    const float* __restrict__ cw, ushort* __restrict__ y2b)
{
  const int bid = blockIdx.x;
  const int logical = (bid & 7)*256 + (bid >> 3);
  const int d = logical & 1023;
  const int b = logical >> 10;
  const int tid = threadIdx.x;
  const int c = tid >> 4, n = tid & 15;
  const float al = alog[d*16 + n];
  const float A = -expf(al);
  const float invA = 1.f/(A + 1e-10f);
  const bool tiny = fabsf(A) < 1e-8f;
  const float dscale = Dp[d];
  const float cw0 = cw[d*4], cw1 = cw[d*4+1], cw2 = cw[d*4+2], cw3 = cw[d*4+3];
  const size_t base = (size_t)b*512*1024 + d;
  const float* pp = p + (size_t)b*512*96;
  const int s0 = c*16;

  __shared__ float sXN[520];
  __shared__ float sDT[512], sZ[512];
  __shared__ float sA[512], sB[512], sH[512];
  __shared__ float sDTW[64];

  if (tid < 64) sDTW[tid] = dtW[d*64 + tid];
  {
    int s = tid - 3;
    sXN[tid] = (s >= 0) ? xn[base + (size_t)s*1024] : 0.f;
    if (tid < 3) sXN[512 + tid] = xn[base + (size_t)(509 + tid)*1024];
    sZ[tid] = z[base + (size_t)tid*1024];
  }
  __syncthreads();

  {
    const us8* pr = (const us8*)(pb64 + (size_t)(b*512 + tid)*64);
    float acc = 0.f;
    #pragma unroll
    for (int q=0;q<8;q++){
      us8 v = pr[q];
      #pragma unroll
      for (int e=0;e<8;e++)
        acc = fmaf(b2f(v[e]), sDTW[q*8+e], acc);
    }
    sDT[tid] = softplus_f(acc + dtb[d]);
  }
  __syncthreads();

  float At[16], inp[16];
  float h = 0.f, pa = 1.f;
  #pragma unroll
  for (int s8=0; s8<16; s8++){
    int s = s0 + s8;
    float uv = silu_f(sXN[s]*cw0 + sXN[s+1]*cw1 + sXN[s+2]*cw2 + sXN[s+3]*cw3);
    float dtv = sDT[s];
    float Bpv = pp[s*96 + 64 + n];
    float a  = expf(dtv*A);
    float bt = tiny ? dtv : (a-1.f)*invA;
    At[s8] = a;
    float ip = bt*Bpv*uv;
    inp[s8] = ip;
    h = a*h + ip;
    pa *= a;
  }
  sA[tid]=pa; sB[tid]=h;
  __syncthreads();
  if (tid < 16){
    float H = 0.f;
    #pragma unroll
    for (int c2=0;c2<32;c2++){
      sH[c2*16+tid] = H;
      H = sA[c2*16+tid]*H + sB[c2*16+tid];
    }
  }
  __syncthreads();

  h = sH[tid];
  #pragma unroll
  for (int s8=0; s8<16; s8++){
    int s = s0 + s8;
    h = At[s8]*h + inp[s8];
    float Cpv = pp[s*96 + 80 + n];
    float cc = Cpv*h;
    cc += __shfl_xor(cc,1);
    cc += __shfl_xor(cc,2);
    cc += __shfl_xor(cc,4);
    cc += __shfl_xor(cc,8);
    if (n==0){
      float uv = silu_f(sXN[s]*cw0 + sXN[s+1]*cw1 + sXN[s+2]*cw2 + sXN[s+3]*cw3);
      float zv = sZ[s];
      y2b[base + (size_t)s*1024] = f2b((cc + uv*dscale) * (zv/(1.f+expf(-zv))));
    }
  }
}

// ---------------- bf16 MFMA GEMM (TM x TN), double-buffered counted-vmcnt ----------------
template<int TM, int TN, int EPI, bool OBF>
__global__ __launch_bounds__(256) void k_bgemm(
    const ushort* __restrict__ A,
    const ushort* __restrict__ W,
    const float* __restrict__ bias,
    const float* __restrict__ resid,
    void* __restrict__ Cout,
    int ldc, int nmax, int K,
    float* __restrict__ pout, ushort* __restrict__ pbout)
{
  constexpr int WN = 2;
  constexpr int WM = 2;
  constexpr int MR = TM/(WM*16);
  constexpr int NR = TN/(WN*16);
  constexpr int LA = TM/32;
  constexpr int LB = TN/32;
  constexpr int LT = LA + LB;

  __shared__ ushort As[2][TM*64] __attribute__((aligned(16)));
  __shared__ ushort Bs[2][TN*64] __attribute__((aligned(16)));
  const int t = threadIdx.x;
  const int w = t >> 6, lane = t & 63;
  const int wn = w % WN, wm = w / WN;
  const int m0 = blockIdx.y * TM;
  const int n0 = blockIdx.x * TN;

  f32x4 acc[MR][NR];
  #pragma unroll
  for (int i=0;i<MR;i++)
    #pragma unroll
    for (int j=0;j<NR;j++) acc[i][j] = (f32x4){0.f,0.f,0.f,0.f};

  const int srow = (lane >> 3);
  const int scol = (((lane & 7) ^ srow)) * 8;

  auto issue = [&](int k0, int buf){
    #pragma unroll
    for (int i=0;i<LA;i++){
      int chunk = i*4 + w;
      int row = chunk*8 + srow;
      gl_lds16(A + (size_t)(m0 + row)*K + k0 + scol, &As[buf][chunk*512]);
    }
    #pragma unroll
    for (int i=0;i<LB;i++){
      int chunk = i*4 + w;
      int row = chunk*8 + srow;
      gl_lds16(W + (size_t)(n0 + row)*K + k0 + scol, &Bs[buf][chunk*512]);
    }
  };

  issue(0, 0);
  const int NS = K >> 6;
  const int fr = lane & 15;
  const int hi = lane >> 4;
  for (int s = 0; s < NS; ++s){
    const int cur = s & 1;
    if (s + 1 < NS){
      issue((s+1)*64, cur^1);
      asm volatile("s_waitcnt vmcnt(%0)" :: "i"(LT) : "memory");
    } else {
      asm volatile("s_waitcnt vmcnt(0)" ::: "memory");
    }
    __builtin_amdgcn_sched_barrier(0);
    __builtin_amdgcn_s_barrier();
    __builtin_amdgcn_sched_barrier(0);
    __builtin_amdgcn_s_setprio(1);
    #pragma unroll
    for (int kk=0; kk<2; ++kk){
      bf16x8 a[MR], b[NR];
      const int cofs = (((kk<<2) | hi) ^ (fr & 7)) * 8;
      #pragma unroll
      for (int am=0; am<MR; am++)
        a[am] = *(const bf16x8*)&As[cur][(wm*(MR*16) + am*16 + fr)*64 + cofs];
      #pragma unroll
      for (int bn=0; bn<NR; bn++)
        b[bn] = *(const bf16x8*)&Bs[cur][(wn*(NR*16) + bn*16 + fr)*64 + cofs];
      #pragma unroll
      for (int am=0; am<MR; am++)
        #pragma unroll
        for (int bn=0; bn<NR; bn++)
          acc[am][bn] = __builtin_amdgcn_mfma_f32_16x16x32_bf16(a[am], b[bn], acc[am][bn], 0, 0, 0);
    }
    __builtin_amdgcn_s_setprio(0);
    __builtin_amdgcn_sched_barrier(0);
    __builtin_amdgcn_s_barrier();
  }

  #pragma unroll
  for (int am=0; am<MR; am++){
    #pragma unroll
    for (int bn=0; bn<NR; bn++){
      int r0 = m0 + wm*(MR*16) + am*16 + ((lane>>4)<<2);
      int cc = n0 + wn*(NR*16) + bn*16 + (lane&15);
      if (cc >= nmax) continue;
      float bv = 0.f;
      if constexpr (EPI==1 || EPI==2 || EPI==5) bv = bias[cc];
      #pragma unroll
      for (int r=0; r<4; r++){
        float v = acc[am][bn][r];
        if constexpr (EPI==1 || EPI==2 || EPI==5) v += bv;
        if constexpr (EPI==2) v = gelu_f(v);
        if constexpr (EPI==4 || EPI==5) v += resid[(size_t)(r0+r)*ldc + cc];
        if constexpr (EPI==6){
          if (cc < 1024) ((float*)Cout)[(size_t)(r0+r)*ldc + cc] = v;
          else {
            int pc = cc - 1024;
            if (pc < 96) pout[(size_t)(r0+r)*96 + pc] = v;
            if (pc < 64) pbout[(size_t)(r0+r)*64 + pc] = f2b(v);
          }
        } else if constexpr (OBF){
          ((ushort*)Cout)[(size_t)(r0+r)*ldc + cc] = f2b(v);
        } else {
          ((float*)Cout)[(size_t)(r0+r)*ldc + cc] = v;
        }
      }
    }
  }
}

// ---------------- head GEMM, fp32 W: 256x128 tile, 512 thr / 8 waves ----------------
// Raw-barrier phases, counted vmcnt: B(s+1) stays in flight across MFMA + top
// barrier + A-issue of next step. vmcnt(4) before ds_write validates B(s) regs.
__global__ __launch_bounds__(512) void k_bgemmHF(
    const ushort* __restrict__ A,
    const float*  __restrict__ W,
    const float* __restrict__ bias,
    float* __restrict__ Cout,
    int ldc, int K)
{
  __shared__ ushort As[256*64] __attribute__((aligned(16)));
  __shared__ ushort Bs[128*64] __attribute__((aligned(16)));
  const int t = threadIdx.x;
  const int w = t >> 6, lane = t & 63;
  const int wn = w & 1, wm = w >> 1;
  const int bid = blockIdx.x;
  const int logical = (bid & 7)*125 + (bid >> 3);
  const int m0 = (logical & 3) * 256;
  const int n0 = (logical >> 2) * 128;

  f32x4 acc[4][4];
  #pragma unroll
  for (int i=0;i<4;i++)
    #pragma unroll
    for (int j=0;j<4;j++) acc[i][j] = (f32x4){0.f,0.f,0.f,0.f};

  const int srow = (lane >> 3);
  const int scolA = (((lane & 7) ^ srow)) * 8;

  const int brow = t >> 2;
  const int bq   = t & 3;
  const float* wp = W + (size_t)(n0 + brow)*K + bq*16;
  const int slot0 = ((bq*2)   ^ (brow & 7)) * 8;
  const int slot1 = ((bq*2+1) ^ (brow & 7)) * 8;

  float4 fb[4];
  #pragma unroll
  for (int j=0;j<4;j++) fb[j] = *(const float4*)(wp + j*4);

  const int fr = lane & 15;
  const int hi = lane >> 4;
  for (int k0 = 0; k0 < K; k0 += 64){
    // top barrier: all waves finished MFMA-reading LDS of previous step.
    // raw (no implicit drain) so the in-flight B prefetch survives.
    __builtin_amdgcn_sched_barrier(0);
    __builtin_amdgcn_s_barrier();
    __builtin_amdgcn_sched_barrier(0);
    #pragma unroll
    for (int i=0;i<4;i++){
      int chunk = i*8 + w;
      int row = chunk*8 + srow;
      gl_lds16(A + (size_t)(m0 + row)*K + k0 + scolA, &As[chunk*512]);
    }
    // B(s) regs must be valid before ds_write: outstanding = B(s)(4,oldest)+A(4)
    asm volatile("s_waitcnt vmcnt(4)" ::: "memory");
    __builtin_amdgcn_sched_barrier(0);
    *(us8*)&Bs[brow*64 + slot0] = cvt2(fb[0], fb[1]);
    *(us8*)&Bs[brow*64 + slot1] = cvt2(fb[2], fb[3]);
    if (k0 + 64 < K){
      #pragma unroll
      for (int j=0;j<4;j++) fb[j] = *(const float4*)(wp + k0 + 64 + j*4);
      // drain A (older than B(s+1)); keep B(s+1) in flight
      asm volatile("s_waitcnt vmcnt(4) lgkmcnt(0)" ::: "memory");
    } else {
      asm volatile("s_waitcnt vmcnt(0) lgkmcnt(0)" ::: "memory");
    }
    __builtin_amdgcn_sched_barrier(0);
    __builtin_amdgcn_s_barrier();
    __builtin_amdgcn_sched_barrier(0);
    __builtin_amdgcn_s_setprio(1);
    #pragma unroll
    for (int kk=0; kk<2; ++kk){
      bf16x8 a[4], b[4];
      const int cofs = (((kk<<2) | hi) ^ (fr & 7)) * 8;
      #pragma unroll
      for (int am=0; am<4; am++)
        a[am] = *(const bf16x8*)&As[(wm*64 + am*16 + fr)*64 + cofs];
      #pragma unroll
      for (int bn=0; bn<4; bn++)
        b[bn] = *(const bf16x8*)&Bs[(wn*64 + bn*16 + fr)*64 + cofs];
      #pragma unroll
      for (int am=0; am<4; am++)
        #pragma unroll
        for (int bn=0; bn<4; bn++)
          acc[am][bn] = __builtin_amdgcn_mfma_f32_16x16x32_bf16(a[am], b[bn], acc[am][bn], 0, 0, 0);
    }
    __builtin_amdgcn_s_setprio(0);
  }

  #pragma unroll
  for (int am=0; am<4; am++){
    #pragma unroll
    for (int bn=0; bn<4; bn++){
      int r0 = m0 + wm*64 + am*16 + ((lane>>4)<<2);
      int cc = n0 + wn*64 + bn*16 + (lane&15);
      float bv = bias[cc];
      #pragma unroll
      for (int r=0; r<4; r++)
        Cout[(size_t)(r0+r)*ldc + cc] = acc[am][bn][r] + bv;
    }
  }
}

extern "C" void kernel_launch(void* const* d_in, const int* in_sizes, int n_in,
                              void* d_out, int out_size, void* d_ws, size_t ws_size,
                              hipStream_t stream)
{
  const int*   ids    = (const int*)d_in[0];
  const int*   tsteps = (const int*)d_in[1];
  const float* tok    = (const float*)d_in[2];
  const float* tw1    = (const float*)d_in[3];
  const float* tb1    = (const float*)d_in[4];
  const float* tw2    = (const float*)d_in[5];
  const float* tb2    = (const float*)d_in[6];
  const float* n1s    = (const float*)d_in[7];
  const float* n1b    = (const float*)d_in[8];
  // d_in[9] = xW, unused by the reference
  const float* zW     = (const float*)d_in[10];
  const float* pW     = (const float*)d_in[11];
  const float* cW     = (const float*)d_in[12];
  const float* dtW    = (const float*)d_in[13];
  const float* dtb    = (const float*)d_in[14];
  const float* alog   = (const float*)d_in[15];
  const float* Dp     = (const float*)d_in[16];
  const float* oW     = (const float*)d_in[17];
  const float* n2s    = (const float*)d_in[18];
  const float* n2b    = (const float*)d_in[19];
  const float* m1W    = (const float*)d_in[20];
  const float* m1b    = (const float*)d_in[21];
  const float* m2W    = (const float*)d_in[22];
  const float* m2b    = (const float*)d_in[23];
  const float* nos    = (const float*)d_in[24];
  const float* nob    = (const float*)d_in[25];
  const float* hW     = (const float*)d_in[26];
  const float* hb     = (const float*)d_in[27];

  float* ws = (float*)d_ws;
  float*  x    = ws;
  float*  xn   = ws + 1048576;
  float*  z    = ws + 2097152;
  float*  p    = ws + 3145728;
  ushort* pb64 = (ushort*)(ws + 3244032);
  float*  t1   = ws + 3276800;
  float*  t2   = ws + 3284992;
  ushort* xnb  = (ushort*)(ws + 3670016);
  ushort* y2b  = (ushort*)(ws + 4194304);
  ushort* h1b  = (ushort*)(ws + 5242880);

  const size_t WBASE = 7340032;
  const size_t WL_US = 10616832;
  const bool big = ws_size >= 179830784ull;
  ushort* wall = (ushort*)(ws + WBASE);
  ushort* whb  = (ushort*)(ws + WBASE + (big ? 4*(WL_US/2) : 0));

  dim3 blk(256);
  if (big)
    k_cvtmega<<<dim3(41472), blk, 0, stream>>>(zW, pW, oW, m1W, m2W, wall);
  k_temb1m<<<dim3(2048), blk, 0, stream>>>(tsteps, tw1, tb1, t1);
  k_temb2<<<dim3(512),  blk, 0, stream>>>(t1, tw2, tb2, t2);

  for (int l=0; l<4; l++){
    ushort* wl = wall + (big ? (size_t)l*WL_US : 0);
    ushort* wzp = wl;
    ushort* wo  = wl + 1179648;
    ushort* wm1 = wl + 2228224;
    ushort* wm2 = wl + 6422528;
    if (!big)
      k_cvtall<<<dim3(10368), blk, 0, stream>>>(
          zW + (size_t)l*1048576, pW + (size_t)l*98304, oW + (size_t)l*1048576,
          m1W + (size_t)l*4194304, m2W + (size_t)l*4194304, wl);
    if (l == 0)
      k_embln<<<dim3(1024), blk, 0, stream>>>(ids, tok, t2, n1s, n1b, x, xn, xnb);
    else
      k_ln<<<dim3(1024), blk, 0, stream>>>(x, n1s + l*1024, n1b + l*1024, xn, xnb);
    // z | p | pb64 in one GEMM (N=1152 packed)
    k_bgemm<64,64,6,false><<<dim3(18,16), blk, 0, stream>>>(xnb, wzp, nullptr, nullptr, z,
                                                            1024, 1152, 1024, p, pb64);
    k_scanf<<<dim3(2048), dim3(512), 0, stream>>>(pb64, dtW + (size_t)l*65536, dtb + l*1024,
                                                  xn, p, alog + l*16384, z, Dp + l*1024,
                                                  cW + l*4096, y2b);
    // x += y2 @ oW^T
    k_bgemm<64,64,4,false><<<dim3(16,16), blk, 0, stream>>>(y2b, wo, nullptr, x, x,
                                                            1024, 1024, 1024, nullptr, nullptr);
    k_ln<<<dim3(1024), blk, 0, stream>>>(x, n2s + l*1024, n2b + l*1024, xn, xnb);
    // m1 (N=4096)
    k_bgemm<64,64,2,true><<<dim3(64,16), blk, 0, stream>>>(xnb, wm1, m1b + l*4096, nullptr, h1b,
                                                           4096, 4096, 1024, nullptr, nullptr);
    // m2 (K=4096)
    k_bgemm<64,64,5,false><<<dim3(16,16), blk, 0, stream>>>(h1b, wm2, m2b + l*1024, x, x,
                                                            1024, 1024, 4096, nullptr, nullptr);
  }
  k_ln<<<dim3(1024), blk, 0, stream>>>(x, nos, nob, xn, xnb);

  if (big){
    k_bgemmHF<<<dim3(1000), dim3(512), 0, stream>>>(xnb, hW, hb, (float*)d_out, 32000, 1024);
  } else {
    for (int h=0; h<2; h++){
      k_cvt<<<dim3(16000), blk, 0, stream>>>(hW + (size_t)h*16384000, whb, 4096000);
      k_bgemm<128,128,1,false><<<dim3(125,8), blk, 0, stream>>>(xnb, whb, hb + h*16000, nullptr,
                                                                (float*)d_out + h*16000,
                                                                32000, 16000, 1024, nullptr, nullptr);
    }
  }
}